// Round 3
// baseline (1909.110 us; speedup 1.0000x reference)
//
#include <hip/hip_runtime.h>

// ---------------------------------------------------------------------------
// NeuralAtom forward, MI355X (gfx950).  FP32 in/out, bf16 MFMA compute.
// B=32 graphs, MAXN=4096, C=256, NS=409 seeds. to_dense_batch == identity.
// This revision:
//  - PIPE template arg: 2-phase double-buffered K-loop ONLY for K>=512
//    (round-2 lesson: 33.8KB LDS halves blocks/CU and hurts small-K GEMMs).
//  - Step 8 (pooled = A1@V, K=4096) runs as split-K x4: Z=128 -> 4 blocks/CU,
//    fp32 partials (transposed store) into reg2, then reduce4_k adds Qp.
// Carried: NSP=416 padded attn strides, V_ produced transposed, TRANS=1
// [k][PKM=132] LDS layout, gload_lds width-16 staging.
// ---------------------------------------------------------------------------

#define BM 128
#define BN 128
#define BKT 32
#define PKM 132   // padded m-stride for TRANS=1 [k][m] LDS tiles
#define NJOBS 33

typedef __attribute__((ext_vector_type(8))) __bf16 bf16x8;
typedef __attribute__((ext_vector_type(4))) __bf16 bf16x4;
typedef __attribute__((ext_vector_type(4))) float  f32x4;

struct CastJobs {
    const float* src[NJOBS];
    __bf16*      dst[NJOBS];
    long         n[NJOBS];
    int          startBlk[NJOBS];
};

// fp32 -> bf16 cast, 33 tensors in one launch. 256 thr x 4 elems = 1024/blk.
__global__ void cast_many_k(CastJobs J)
{
    int b = blockIdx.x;
    int j = 0;
#pragma unroll
    for (int t = 0; t < NJOBS; t++) { if (J.startBlk[t] <= b) j = t; }
    long idx = ((long)(b - J.startBlk[j]) * 256 + threadIdx.x) * 4;
    if (idx < J.n[j]) {
        f32x4 v = *(const f32x4*)(J.src[j] + idx);
        bf16x4 o;
        o[0] = (__bf16)v[0]; o[1] = (__bf16)v[1];
        o[2] = (__bf16)v[2]; o[3] = (__bf16)v[3];
        *(bf16x4*)(J.dst[j] + idx) = o;
    }
}

__device__ __forceinline__ void gload_lds16(const __bf16* g, __bf16* l)
{
    __builtin_amdgcn_global_load_lds(
        (const __attribute__((address_space(1))) void*)g,
        (__attribute__((address_space(3))) void*)l, 16, 0, 0);
}

// Stage phase 1: issue loads for one tile.
//  TRANS=0 fast (aligned, fully in-bounds): global_load_lds direct -> lds,
//    returns true (no write phase needed).
//  otherwise: guarded global->reg loads into rv, returns false.
// TRANS=0 target layout: linear [128 r][32 k]. TRANS=1: [32 k][PKM m].
template<int TRANS>
__device__ __forceinline__ bool stage_load(bf16x8 (&rv)[2], __bf16* __restrict__ lds,
                                           const __bf16* __restrict__ G,
                                           int ld, int r0, int Rg,
                                           int k0, int K, int tid)
{
    if (TRANS == 0) {
        const bool fast = ((ld & 7) == 0) && (r0 + BM <= Rg) && (k0 + BKT <= K);
        if (fast) {
#pragma unroll
            for (int i = 0; i < 2; i++) {
                int v = tid + i * 256;            // linear in lane order
                int r = v >> 2, kc = (v & 3) * 8;
                gload_lds16(G + (long)(r0 + r) * ld + (k0 + kc), lds + v * 8);
            }
            return true;
        }
#pragma unroll
        for (int i = 0; i < 2; i++) {
            int v = tid + i * 256;
            int r = v >> 2, kc = (v & 3) * 8;
            int gm = r0 + r, gk = k0 + kc;
            bf16x8 val;
#pragma unroll
            for (int j = 0; j < 8; j++) val[j] = (__bf16)0.0f;
            if (gm < Rg) {
                if (((ld & 7) == 0) && (gk + 8 <= K)) {
                    val = *(const bf16x8*)(G + (long)gm * ld + gk);
                } else {
#pragma unroll
                    for (int j = 0; j < 8; j++)
                        if (gk + j < K) val[j] = G[(long)gm * ld + gk + j];
                }
            }
            rv[i] = val;
        }
        return false;
    } else {
#pragma unroll
        for (int i = 0; i < 2; i++) {
            int v = tid + i * 256;
            int kk = v >> 4;                      // 0..31 k-row
            int mc = (v & 15) * 8;                // m-col group
            int gk = k0 + kk, gm = r0 + mc;
            bf16x8 val;
#pragma unroll
            for (int j = 0; j < 8; j++) val[j] = (__bf16)0.0f;
            if (gk < K) {
                if (((ld & 7) == 0) && (gm + 8 <= Rg)) {
                    val = *(const bf16x8*)(G + (long)gk * ld + gm);
                } else {
#pragma unroll
                    for (int j = 0; j < 8; j++)
                        if (gm + j < Rg) val[j] = G[(long)gk * ld + gm + j];
                }
            }
            rv[i] = val;
        }
        return false;
    }
}

// Stage phase 2: reg -> LDS writes (no-op for the gload_lds fast path).
template<int TRANS>
__device__ __forceinline__ void stage_write(const bf16x8 (&rv)[2], __bf16* __restrict__ lds,
                                            int tid, bool fast)
{
    if (TRANS == 0) {
        if (fast) return;
#pragma unroll
        for (int i = 0; i < 2; i++)
            *(bf16x8*)(lds + (tid + i * 256) * 8) = rv[i];   // 16B aligned
    } else {
#pragma unroll
        for (int i = 0; i < 2; i++) {
            int v = tid + i * 256;
            int kk = v >> 4, mc = (v & 15) * 8;
            bf16x4 lo, hi;
            lo[0] = rv[i][0]; lo[1] = rv[i][1]; lo[2] = rv[i][2]; lo[3] = rv[i][3];
            hi[0] = rv[i][4]; hi[1] = rv[i][5]; hi[2] = rv[i][6]; hi[3] = rv[i][7];
            *(bf16x4*)(lds + kk * PKM + mc)     = lo;   // 8B aligned (PKM*2=264)
            *(bf16x4*)(lds + kk * PKM + mc + 4) = hi;
        }
    }
}

// Fragment read + 16 MFMA for one staged K-tile.
template<int AT, int BT>
__device__ __forceinline__ void frag_mfma(const __bf16* __restrict__ Ac,
                                          const __bf16* __restrict__ Bc,
                                          f32x4 (&acc)[4][4],
                                          int wm, int wn, int l15, int lq)
{
    bf16x8 af[4], bfr[4];
    if (AT == 0) {
#pragma unroll
        for (int i = 0; i < 4; i++)
            af[i] = *(const bf16x8*)(Ac + (wm + i * 16 + l15) * BKT + lq * 8);
    } else {
#pragma unroll
        for (int i = 0; i < 4; i++) {
            int m = wm + i * 16 + l15;
#pragma unroll
            for (int j = 0; j < 8; j++) af[i][j] = Ac[(lq * 8 + j) * PKM + m];
        }
    }
    if (BT == 1) {
#pragma unroll
        for (int j = 0; j < 4; j++)
            bfr[j] = *(const bf16x8*)(Bc + (wn + j * 16 + l15) * BKT + lq * 8);
    } else {
#pragma unroll
        for (int j = 0; j < 4; j++) {
            int n = wn + j * 16 + l15;
#pragma unroll
            for (int jj = 0; jj < 8; jj++) bfr[j][jj] = Bc[(lq * 8 + jj) * PKM + n];
        }
    }
#pragma unroll
    for (int i = 0; i < 4; i++)
#pragma unroll
        for (int j = 0; j < 4; j++)
            acc[i][j] = __builtin_amdgcn_mfma_f32_16x16x32_bf16(af[i], bfr[j], acc[i][j], 0, 0, 0);
}

// Generic MFMA GEMM: out = epilogue( A x B * oscale ).
// AT=0: A[M,K].  AT=1: A[K,M] (k-major; staged TRANS=1, scalar frag reads).
// BT=1: B=W[N,K] (X@W^T).  BT=0: B[K,N] (k-major; staged TRANS=1).
// PIPE=1: double-buffered 2-phase K-loop (use only for large K; costs 2x LDS).
// Ms/Ns: staging guards (padded where buffer allows -> full vec loads).
// z offsets: off = (z&31)*Lo + (z>>5)*Hi.
// act: 0 none, 1 scaled-SiLU, 2 relu.  resMode: 0/1=(r+y)/sqrt2/2=r+y.
// storeT: store element (row,col) at out[col*ldo+row] (fp32 or bf16);
//         residual also read transposed: Rb[col*ldr+row].
template<int AT, int BT, int PIPE>
__launch_bounds__(256, 2)
__global__ void gemm_k(const __bf16* __restrict__ A, long aLo, long aHi, int lda, int Ms,
                       const __bf16* __restrict__ Bm, long bLo, long bHi, int ldb, int Ns,
                       const __bf16* __restrict__ bias,
                       const __bf16* __restrict__ res, long rLo, long rHi, int ldr, int resMode,
                       float* __restrict__ outF, __bf16* __restrict__ outB,
                       long oLo, long oHi, int ldo, int storeT,
                       int M, int N, int K, float oscale, int act)
{
    constexpr int BTT = (BT == 1) ? 0 : 1;
    constexpr int NBUF = PIPE ? 2 : 1;
    __shared__ __align__(16) __bf16 As[NBUF * BKT * PKM];
    __shared__ __align__(16) __bf16 Bs[NBUF * BKT * PKM];

    const int tid = threadIdx.x;
    const int z = blockIdx.z;
    const long zl = (long)(z & 31), zh = (long)(z >> 5);
    const __bf16* Ab = A + zl * aLo + zh * aHi;
    const __bf16* Bb = Bm + zl * bLo + zh * bHi;
    const int m0 = blockIdx.x * BM;
    const int n0 = blockIdx.y * BN;

    f32x4 acc[4][4];
#pragma unroll
    for (int i = 0; i < 4; i++)
#pragma unroll
        for (int j = 0; j < 4; j++)
#pragma unroll
            for (int r = 0; r < 4; r++) acc[i][j][r] = 0.0f;

    const int wv = tid >> 6;
    const int lane = tid & 63;
    const int wm = (wv >> 1) * 64;
    const int wn = (wv & 1) * 64;
    const int l15 = lane & 15;
    const int lq  = lane >> 4;

    if (PIPE == 0) {
        for (int k0 = 0; k0 < K; k0 += BKT) {
            bf16x8 ra[2], rb[2];
            bool fa = stage_load<AT>(ra, As, Ab, lda, m0, Ms, k0, K, tid);
            bool fb = stage_load<BTT>(rb, Bs, Bb, ldb, n0, Ns, k0, K, tid);
            stage_write<AT>(ra, As, tid, fa);
            stage_write<BTT>(rb, Bs, tid, fb);
            __syncthreads();
            frag_mfma<AT, BT>(As, Bs, acc, wm, wn, l15, lq);
            __syncthreads();
        }
    } else {
        constexpr int TSZ = BKT * PKM;
        const int nt = (K + BKT - 1) / BKT;
        bf16x8 ra[2], rb[2];
        bool fa = stage_load<AT>(ra, As, Ab, lda, m0, Ms, 0, K, tid);
        bool fb = stage_load<BTT>(rb, Bs, Bb, ldb, n0, Ns, 0, K, tid);
        stage_write<AT>(ra, As, tid, fa);
        stage_write<BTT>(rb, Bs, tid, fb);
        __syncthreads();
        int cur = 0;
        for (int t = 0; t < nt; t++) {
            const bool nxt = (t + 1 < nt);
            if (nxt) {   // issue-early: loads for tile t+1 (disjoint buffer)
                fa = stage_load<AT>(ra, As + (cur ^ 1) * TSZ, Ab, lda, m0, Ms, (t + 1) * BKT, K, tid);
                fb = stage_load<BTT>(rb, Bs + (cur ^ 1) * TSZ, Bb, ldb, n0, Ns, (t + 1) * BKT, K, tid);
            }
            frag_mfma<AT, BT>(As + cur * TSZ, Bs + cur * TSZ, acc, wm, wn, l15, lq);
            if (nxt) {   // write-late, then one barrier
                stage_write<AT>(ra, As + (cur ^ 1) * TSZ, tid, fa);
                stage_write<BTT>(rb, Bs + (cur ^ 1) * TSZ, tid, fb);
                __syncthreads();
                cur ^= 1;
            }
        }
    }

    const __bf16* Rb = res ? (res + zl * rLo + zh * rHi) : (const __bf16*)nullptr;
    const long ob = zl * oLo + zh * oHi;
#pragma unroll
    for (int i = 0; i < 4; i++) {
#pragma unroll
        for (int j = 0; j < 4; j++) {
            int col = n0 + wn + j * 16 + l15;
            if (col >= N) continue;
            float bcol = bias ? (float)bias[col] : 0.0f;
            int row0 = m0 + wm + i * 16 + lq * 4;
            if (!storeT) {
#pragma unroll
                for (int r = 0; r < 4; r++) {
                    int row = row0 + r;
                    if (row >= M) continue;
                    float v = acc[i][j][r] * oscale + bcol;
                    if (act == 1) {            // stable scaled-SiLU
                        float e = __expf(-fabsf(v));
                        float sig = (v >= 0.0f) ? 1.0f / (1.0f + e) : e / (1.0f + e);
                        v = v * sig * 1.6666666666666667f;
                    } else if (act == 2) {
                        v = fmaxf(v, 0.0f);
                    }
                    if (resMode) {
                        float rv = (float)Rb[(long)row * ldr + col];
                        v = (resMode == 1) ? (rv + v) * 0.70710678118654752f : (rv + v);
                    }
                    long oi = ob + (long)row * ldo + col;
                    if (outF) outF[oi] = v;
                    else      outB[oi] = (__bf16)v;
                }
            } else {
                // transposed store; rows r are consecutive -> vec4 pack
                if (row0 + 3 < M) {
                    bf16x4 rv4;
                    if (resMode) rv4 = *(const bf16x4*)(Rb + (long)col * ldr + row0);
                    float vs[4];
#pragma unroll
                    for (int r = 0; r < 4; r++) {
                        float v = acc[i][j][r] * oscale + bcol;
                        if (act == 1) {
                            float e = __expf(-fabsf(v));
                            float sig = (v >= 0.0f) ? 1.0f / (1.0f + e) : e / (1.0f + e);
                            v = v * sig * 1.6666666666666667f;
                        } else if (act == 2) {
                            v = fmaxf(v, 0.0f);
                        }
                        if (resMode) {
                            float rv = (float)rv4[r];
                            v = (resMode == 1) ? (rv + v) * 0.70710678118654752f : (rv + v);
                        }
                        vs[r] = v;
                    }
                    if (outF) {
                        f32x4 o4; o4[0] = vs[0]; o4[1] = vs[1]; o4[2] = vs[2]; o4[3] = vs[3];
                        *(f32x4*)(outF + ob + (long)col * ldo + row0) = o4;
                    } else {
                        bf16x4 ov;
                        ov[0] = (__bf16)vs[0]; ov[1] = (__bf16)vs[1];
                        ov[2] = (__bf16)vs[2]; ov[3] = (__bf16)vs[3];
                        *(bf16x4*)(outB + ob + (long)col * ldo + row0) = ov;
                    }
                } else {
#pragma unroll
                    for (int r = 0; r < 4; r++) {
                        int row = row0 + r;
                        if (row >= M) continue;
                        float v = acc[i][j][r] * oscale + bcol;
                        if (act == 1) {
                            float e = __expf(-fabsf(v));
                            float sig = (v >= 0.0f) ? 1.0f / (1.0f + e) : e / (1.0f + e);
                            v = v * sig * 1.6666666666666667f;
                        } else if (act == 2) {
                            v = fmaxf(v, 0.0f);
                        }
                        if (resMode) {
                            float rv = (float)Rb[(long)col * ldr + row];
                            v = (resMode == 1) ? (rv + v) * 0.70710678118654752f : (rv + v);
                        }
                        if (outF) outF[ob + (long)col * ldo + row] = v;
                        else      outB[ob + (long)col * ldo + row] = (__bf16)v;
                    }
                }
            }
        }
    }
}

// Sum 4 split-K fp32 partials [4][32][NS][256] + Qp[NS][256] -> bf16 [32][NS][256].
__global__ void reduce4_k(const float* __restrict__ P, const __bf16* __restrict__ Qp,
                          __bf16* __restrict__ out)
{
    long idx = (long)blockIdx.x * 256 + threadIdx.x;       // one unit = 4 ch
    long g = idx / (409 * 64);
    long r = idx - g * (409 * 64);
    long s = r >> 6;
    int  c4 = (int)(r & 63) * 4;
    long base = (g * 409 + s) * 256 + c4;
    const long SP = 32L * 409 * 256;
    f32x4 a0 = *(const f32x4*)(P + base);
    f32x4 a1 = *(const f32x4*)(P + base + SP);
    f32x4 a2 = *(const f32x4*)(P + base + 2 * SP);
    f32x4 a3 = *(const f32x4*)(P + base + 3 * SP);
    bf16x4 q = *(const bf16x4*)(Qp + s * 256 + c4);
    bf16x4 o;
#pragma unroll
    for (int k = 0; k < 4; k++)
        o[k] = (__bf16)(a0[k] + a1[k] + a2[k] + a3[k] + (float)q[k]);
    *(bf16x4*)(out + base) = o;
}

// Row softmax over length L (stride ldS fp32 in, ldA bf16 out), zero-fills
// columns [L, Lw).  One wave per row.
__global__ void rowsoftmax_k(const float* __restrict__ S, __bf16* __restrict__ A,
                             long rows, int L, int ldS, int ldA, int Lw)
{
    long row = (long)blockIdx.x * 4 + (threadIdx.x >> 6);
    if (row >= rows) return;
    int lane = threadIdx.x & 63;
    const float* Sr = S + row * (long)ldS;
    float v[7];
    int cnt = 0;
    for (int q = lane; q < L; q += 64) v[cnt++] = Sr[q];
    float m = -3.0e38f;
    for (int c = 0; c < cnt; c++) m = fmaxf(m, v[c]);
#pragma unroll
    for (int off = 32; off > 0; off >>= 1) m = fmaxf(m, __shfl_xor(m, off));
    float s = 0.0f;
    for (int c = 0; c < cnt; c++) s += __expf(v[c] - m);
#pragma unroll
    for (int off = 32; off > 0; off >>= 1) s += __shfl_xor(s, off);
    float inv = 1.0f / s;                  // s >= 1
    cnt = 0;
    for (int q = lane; q < Lw; q += 64) {
        float o = 0.0f;
        if (q < L) { o = __expf(v[cnt] - m) * inv; cnt++; }
        A[row * (long)ldA + q] = (__bf16)o;
    }
}

// LayerNorm over C=256 (eps 1e-5), one wave per row.
__global__ void ln_k(const __bf16* __restrict__ X, __bf16* __restrict__ Y,
                     const __bf16* __restrict__ gamma, const __bf16* __restrict__ beta,
                     int rows)
{
    int row = blockIdx.x * 4 + (threadIdx.x >> 6);
    if (row >= rows) return;
    int lane = threadIdx.x & 63;
    bf16x4 xv = *(const bf16x4*)(X + (long)row * 256 + lane * 4);
    float v0 = (float)xv[0], v1 = (float)xv[1], v2 = (float)xv[2], v3 = (float)xv[3];
    float s = v0 + v1 + v2 + v3;
#pragma unroll
    for (int off = 32; off > 0; off >>= 1) s += __shfl_xor(s, off);
    float mean = s * (1.0f / 256.0f);
    float d0 = v0 - mean, d1 = v1 - mean, d2 = v2 - mean, d3 = v3 - mean;
    float q = d0 * d0 + d1 * d1 + d2 * d2 + d3 * d3;
#pragma unroll
    for (int off = 32; off > 0; off >>= 1) q += __shfl_xor(q, off);
    float sc = rsqrtf(q * (1.0f / 256.0f) + 1e-5f);
    bf16x4 gv = *(const bf16x4*)(gamma + lane * 4);
    bf16x4 bv = *(const bf16x4*)(beta + lane * 4);
    bf16x4 ov;
    ov[0] = (__bf16)(d0 * sc * (float)gv[0] + (float)bv[0]);
    ov[1] = (__bf16)(d1 * sc * (float)gv[1] + (float)bv[1]);
    ov[2] = (__bf16)(d2 * sc * (float)gv[2] + (float)bv[2]);
    ov[3] = (__bf16)(d3 * sc * (float)gv[3] + (float)bv[3]);
    *(bf16x4*)(Y + (long)row * 256 + lane * 4) = ov;
}

// ws too small -> unambiguous sentinel (absmax ~12345), no OOB.
__global__ void sentinel_k(float* out, long n)
{
    long i = (long)blockIdx.x * blockDim.x + threadIdx.x;
    if (i < n) out[i] = 12345.0f;
}

static void G(hipStream_t st, int AT, int BT,
              const __bf16* A, long aLo, long aHi, int lda, int Ms,
              const __bf16* B, long bLo, long bHi, int ldb, int Ns,
              const __bf16* bias,
              const __bf16* res, long rLo, long rHi, int ldr, int resMode,
              float* outF, __bf16* outB, long oLo, long oHi, int ldo, int storeT,
              int M, int N, int K, int Z, float oscale, int act)
{
    dim3 grid((M + BM - 1) / BM, (N + BN - 1) / BN, Z), blk(256, 1, 1);
    const bool pipe = (K >= 512);
#define GARGS A, aLo, aHi, lda, Ms, B, bLo, bHi, ldb, Ns, bias, res, rLo, rHi, ldr, resMode, \
              outF, outB, oLo, oHi, ldo, storeT, M, N, K, oscale, act
    if (AT == 0 && BT == 1) {
        if (pipe) gemm_k<0, 1, 1><<<grid, blk, 0, st>>>(GARGS);
        else      gemm_k<0, 1, 0><<<grid, blk, 0, st>>>(GARGS);
    } else if (AT == 0 && BT == 0) {
        if (pipe) gemm_k<0, 0, 1><<<grid, blk, 0, st>>>(GARGS);
        else      gemm_k<0, 0, 0><<<grid, blk, 0, st>>>(GARGS);
    } else {
        if (pipe) gemm_k<1, 0, 1><<<grid, blk, 0, st>>>(GARGS);
        else      gemm_k<1, 0, 0><<<grid, blk, 0, st>>>(GARGS);
    }
#undef GARGS
}

extern "C" void kernel_launch(void* const* d_in, const int* in_sizes, int n_in,
                              void* d_out, int out_size, void* d_ws, size_t ws_size,
                              hipStream_t stream)
{
    (void)in_sizes; (void)n_in;
    float* OUT = (float*)d_out;

    const int TOT = 131072, NC = 256, NS = 409, MX = 4096;
    const int NSP = 416;                      // padded NS stride (mult of 8)
    const int NSB = 32 * NS;                  // 13088
    const long NTC = (long)TOT * NC;          // 33.5M elems
    const int GCH = 4;                        // graphs per score chunk

    // ---- param cast table (d_in index -> bf16 param block) ----
    static const int  pidx[NJOBS] = {0,2,3,4,5,6,7,8,9,10,11,12,13,14,15,16,
                                     17,18,19,20,21,22,23,24,25,26,27,28,29,30,31,32,33};
    static const long pn[NJOBS]   = {33554432,65536,65536,104704,
                                     65536,256,65536,256,65536,256,65536,256,
                                     256,256,256,256,
                                     65536,256,65536,256,65536,256,65536,256,
                                     256,256,256,256,
                                     65536,65536,65536,65536,65536};
    long ptot = 0;
    for (int j = 0; j < NJOBS; j++) ptot += pn[j];   // 34,646,272 elems

    char* w = (char*)d_ws;
    size_t off = 0;
    auto take = [&](size_t bytes) -> char* {
        char* p = w + off;
        off += (bytes + 255) & ~(size_t)255;
        return p;
    };
    char* pblk = take((size_t)ptot * 2);                  // 69.3MB bf16 params
    char* reg0 = take((size_t)64 * NS * NSP * 4);         // fp32 scores (43.6MB)
    char* reg1 = take((size_t)32 * MX * NSP * 2);         // A1T (padded) -> t
    char* reg2 = take((size_t)NTC * 2);                   // K_ -> splitK partials -> h_back -> u
    char* reg3 = take((size_t)NTC * 2);                   // V_T -> A2T -> tmp/tmp2
    __bf16* QP  = (__bf16*)take((size_t)NS * NC * 2);
    __bf16* sb0 = (__bf16*)take((size_t)NSB * NC * 2);
    __bf16* sb1 = (__bf16*)take((size_t)NSB * NC * 2);
    __bf16* sb2 = (__bf16*)take((size_t)NSB * NC * 2);
    __bf16* sb3 = (__bf16*)take((size_t)NSB * NC * 2);
    __bf16* sb4 = (__bf16*)take((size_t)NSB * NC * 2);
    __bf16* sb5 = (__bf16*)take((size_t)NSB * NC * 2);

    if (off > ws_size) {
        long n = out_size;
        sentinel_k<<<(int)((n + 255) / 256), 256, 0, stream>>>(OUT, n);
        return;
    }

    // Build cast jobs + param pointers.
    CastJobs J;
    __bf16* P[NJOBS];
    {
        long cum = 0;
        int blk = 0;
        for (int j = 0; j < NJOBS; j++) {
            J.src[j] = (const float*)d_in[pidx[j]];
            P[j] = (__bf16*)pblk + cum;
            J.dst[j] = P[j];
            J.n[j] = pn[j];
            J.startBlk[j] = blk;
            blk += (int)((pn[j] + 1023) / 1024);
            cum += pn[j];
        }
        cast_many_k<<<blk, 256, 0, stream>>>(J);
    }
    const __bf16 *hB = P[0], *Wpre1 = P[1], *Wpre2 = P[2], *Sseed = P[3];
    const __bf16 *pWq = P[4], *pbq = P[5], *pWk = P[6], *pbk = P[7];
    const __bf16 *pWv = P[8], *pbv = P[9], *pWo = P[10], *pbo = P[11];
    const __bf16 *pg0 = P[12], *pb0 = P[13], *pg1 = P[14], *pb1 = P[15];
    const __bf16 *iWq = P[16], *ibq = P[17], *iWk = P[18], *ibk = P[19];
    const __bf16 *iWv = P[20], *ibv = P[21], *iWo = P[22], *ibo = P[23];
    const __bf16 *ig0 = P[24], *ib0 = P[25], *ig1 = P[26], *ib1 = P[27];
    const __bf16 *Whead = P[28], *Wr1a = P[29], *Wr1b = P[30];
    const __bf16 *Wr2a = P[31], *Wr2b = P[32];

    float*  STs = (float*)reg0;               // score-T chunk [GCH, MX, NSP] fp32
    float*  S2T = (float*)reg0;               // intra score-T [64, NS, NSP] fp32
    __bf16* T1  = (__bf16*)reg1;
    __bf16* A1T = (__bf16*)reg1;              // [32, MX, NSP], pad cols zeroed
    __bf16* Tt  = (__bf16*)reg1;              // t (after A1T dead)
    __bf16* Kb  = (__bf16*)reg2;
    float*  PP  = (float*)reg2;               // split-K partials (after K_ dead)
    __bf16* HB  = (__bf16*)reg2;              // h_back (after partials dead)
    __bf16* Ub  = (__bf16*)reg2;              // u (after HB dead)
    __bf16* Vt  = (__bf16*)reg3;              // V_^T [32, 256, 4096]
    __bf16* A2T = (__bf16*)reg3;              // [64, NS, NSP] (after V_T dead)
    __bf16* Tm  = (__bf16*)reg3;              // tmp/tmp2 (after A2T dead)
    __bf16* HR  = (__bf16*)d_out;             // bf16 hres scratch inside d_out

    // 1: T1 = silu_s(h @ Wpre1^T)
    G(stream, 0, 1, hB, 0, 0, 256, TOT, Wpre1, 0, 0, 256, 256, nullptr,
      nullptr, 0, 0, 0, 0, nullptr, T1, 0, 0, 256, 0, TOT, 256, 256, 1, 1.0f, 1);
    // 2: hres = (h + silu_s(T1 @ Wpre2^T)) / sqrt2  -> d_out scratch
    G(stream, 0, 1, T1, 0, 0, 256, TOT, Wpre2, 0, 0, 256, 256, nullptr,
      hB, 0, 0, 256, 1, nullptr, HR, 0, 0, 256, 0, TOT, 256, 256, 1, 1.0f, 1);
    // 3: K_
    G(stream, 0, 1, HR, 0, 0, 256, TOT, pWk, 0, 0, 256, 256, pbk,
      nullptr, 0, 0, 0, 0, nullptr, Kb, 0, 0, 256, 0, TOT, 256, 256, 1, 1.0f, 0);
    // 4: V_^T via transposed store: Vt[g][c][n] = hres@pWv^T + pbv
    G(stream, 0, 1, HR, (long)MX * NC, 0, 256, MX, pWv, 0, 0, 256, 256, pbv,
      nullptr, 0, 0, 0, 0, nullptr, Vt, (long)NC * MX, 0, MX, 1, MX, 256, 256, 32, 1.0f, 0);
    // 5: Qp = S @ pWq^T + pbq
    G(stream, 0, 1, Sseed, 0, 0, 256, NS, pWq, 0, 0, 256, 256, pbq,
      nullptr, 0, 0, 0, 0, nullptr, QP, 0, 0, 256, 0, NS, 256, 256, 1, 1.0f, 0);
    // 6,7: chunked score-T = K_ @ Qp^T / 16 (fp32, ldo=NSP), ROW softmax -> A1T
    for (int c = 0; c < 32 / GCH; c++) {
        const __bf16* Kc = Kb + (size_t)c * GCH * MX * NC;
        G(stream, 0, 1, Kc, (long)MX * NC, 0, 256, MX, QP, 0, 0, 256, NS, nullptr,
          nullptr, 0, 0, 0, 0, STs, nullptr, (long)MX * NSP, 0, NSP, 0,
          MX, NS, 256, GCH, 0.0625f, 0);
        rowsoftmax_k<<<dim3(GCH * MX / 4), 256, 0, stream>>>(
            STs, A1T + (size_t)c * GCH * MX * NSP, (long)GCH * MX, NS, NSP, NSP, NSP);
    }
    // 8a: split-K x4 partial pooled^T: PP[sp][g][s][c] (fp32, transposed store)
    //     z = sp*32 + g; A = Vt[g] col-offset sp*1024; B = A1T[g] row-offset.
    G(stream, 0, 0, Vt, (long)NC * MX, 1024, MX, NC,
      A1T, (long)MX * NSP, 1024L * NSP, NSP, NSP, nullptr,
      nullptr, 0, 0, 0, 0, PP, nullptr, (long)NS * NC, 32L * NS * NC, NC, 1,
      NC, NS, 1024, 128, 1.0f, 0);
    // 8b: pooled[g][s][c] = Qp[s][c] + sum_sp PP
    reduce4_k<<<dim3((unsigned)((32L * NS * 64) / 256)), 256, 0, stream>>>(PP, QP, sb0);
    // 9-11: LN, +relu(Wo), LN
    ln_k<<<dim3(NSB / 4), 256, 0, stream>>>(sb0, sb1, pg0, pb0, NSB);
    G(stream, 0, 1, sb1, 0, 0, 256, NSB, pWo, 0, 0, 256, 256, pbo,
      sb1, 0, 0, 256, 2, nullptr, sb2, 0, 0, 256, 0, NSB, 256, 256, 1, 1.0f, 2);
    ln_k<<<dim3(NSB / 4), 256, 0, stream>>>(sb2, sb0, pg1, pb1, NSB);
    // 12: Qi, Ki, Vi
    G(stream, 0, 1, sb0, 0, 0, 256, NSB, iWq, 0, 0, 256, 256, ibq,
      nullptr, 0, 0, 0, 0, nullptr, sb1, 0, 0, 256, 0, NSB, 256, 256, 1, 1.0f, 0);
    G(stream, 0, 1, sb0, 0, 0, 256, NSB, iWk, 0, 0, 256, 256, ibk,
      nullptr, 0, 0, 0, 0, nullptr, sb2, 0, 0, 256, 0, NSB, 256, 256, 1, 1.0f, 0);
    G(stream, 0, 1, sb0, 0, 0, 256, NSB, iWv, 0, 0, 256, 256, ibv,
      nullptr, 0, 0, 0, 0, nullptr, sb3, 0, 0, 256, 0, NSB, 256, 256, 1, 1.0f, 0);
    // 13: intra score-T S2T[hb,k,q] = Ki_h @ Qi_h^T / 16  (z = head*32 + b)
    G(stream, 0, 1, sb2, (long)NS * NC, 128, 256, NS, sb1, (long)NS * NC, 128, 256, NS, nullptr,
      nullptr, 0, 0, 0, 0, S2T, nullptr, (long)NS * NSP, 32L * NS * NSP, NSP, 0,
      NS, NS, 128, 64, 0.0625f, 0);
    // 14: A2T = row softmax over q (pad zeroed)
    rowsoftmax_k<<<dim3(64 * NS / 4), 256, 0, stream>>>(S2T, A2T, 64L * NS, NS, NSP, NSP, NSP);
    // 15: out2 = Qi_head + A2 @ Vi_head   (A2[q,k] = A2T[k,q]: AT=1, lda=NSP)
    G(stream, 1, 0, A2T, (long)NS * NSP, 32L * NS * NSP, NSP, NSP,
      sb3, (long)NS * NC, 128, 256, 128, nullptr,
      sb1, (long)NS * NC, 128, 256, 2, nullptr, sb4, (long)NS * NC, 128, 256, 0,
      NS, 128, NS, 64, 1.0f, 0);
    // 16: LN, +relu(iWo), LN -> NAs2 (sb1)
    ln_k<<<dim3(NSB / 4), 256, 0, stream>>>(sb4, sb5, ig0, ib0, NSB);
    G(stream, 0, 1, sb5, 0, 0, 256, NSB, iWo, 0, 0, 256, 256, ibo,
      sb5, 0, 0, 256, 2, nullptr, sb4, 0, 0, 256, 0, NSB, 256, 256, 1, 1.0f, 2);
    ln_k<<<dim3(NSB / 4), 256, 0, stream>>>(sb4, sb1, ig1, ib1, NSB);
    // 17: h_back[n,c] = sum_s A1T[n,s] * NAs2[s,c]; K=416 (A1T pad cols are 0,
    //     so B's garbage rows s>=409 are annihilated) -> fully vectorized
    G(stream, 0, 0, A1T, (long)MX * NSP, 0, NSP, MX, sb1, (long)NS * NC, 0, 256, 256, nullptr,
      nullptr, 0, 0, 0, 0, nullptr, HB, (long)MX * NC, 0, 256, 0, MX, 256, 416, 32, 1.0f, 0);
    // 18: t = silu_s(h_back @ Whead^T)   (A1T dead -> reg1)
    G(stream, 0, 1, HB, 0, 0, 256, TOT, Whead, 0, 0, 256, 256, nullptr,
      nullptr, 0, 0, 0, 0, nullptr, Tt, 0, 0, 256, 0, TOT, 256, 256, 1, 1.0f, 1);
    // 19: res_layer r1
    G(stream, 0, 1, Tt, 0, 0, 256, TOT, Wr1a, 0, 0, 256, 256, nullptr,
      nullptr, 0, 0, 0, 0, nullptr, Tm, 0, 0, 256, 0, TOT, 256, 256, 1, 1.0f, 1);
    G(stream, 0, 1, Tm, 0, 0, 256, TOT, Wr1b, 0, 0, 256, 256, nullptr,
      Tt, 0, 0, 256, 1, nullptr, Ub, 0, 0, 256, 0, TOT, 256, 256, 1, 1.0f, 1);
    // 20: res_layer r2 -> OUT (fp32)
    G(stream, 0, 1, Ub, 0, 0, 256, TOT, Wr2a, 0, 0, 256, 256, nullptr,
      nullptr, 0, 0, 0, 0, nullptr, Tm, 0, 0, 256, 0, TOT, 256, 256, 1, 1.0f, 1);
    G(stream, 0, 1, Tm, 0, 0, 256, TOT, Wr2b, 0, 0, 256, 256, nullptr,
      Ub, 0, 0, 256, 1, OUT, nullptr, 0, 0, 256, 0, TOT, 256, 256, 1, 1.0f, 1);
}

// Round 4
// 1482.603 us; speedup vs baseline: 1.2877x; 1.2877x over previous
//
#include <hip/hip_runtime.h>

// ---------------------------------------------------------------------------
// NeuralAtom forward, MI355X (gfx950).  FP32 in/out, bf16 MFMA compute.
// B=32 graphs, MAXN=4096, C=256, NS=409 seeds. to_dense_batch == identity.
// This revision: chain fusion.
//  - fuse_front_k: h -> T1 -> hres -> {K_ row-major, V_T transposed}, one
//    kernel, 64-row LDS tiles, weights direct-from-L2.  Replaces steps 1-4
//    (737 MB HBM -> 268 MB).
//  - fuse_tail_k: HB -> t -> tmp -> u -> tmp2 -> OUT fp32.  Replaces steps
//    18-20 (5 GEMMs, ~900 MB -> ~200 MB).
// Carried: split-K x4 step 8 + reduce, PIPE double-buffer only for the K=1024
// split-K GEMM, NSP=416 padded attn strides, TRANS=1 [k][PKM] LDS staging.
// ---------------------------------------------------------------------------

#define BM 128
#define BN 128
#define BKT 32
#define PKM 132   // padded m-stride for TRANS=1 [k][m] LDS tiles
#define XS  264   // padded row stride for fused-chain LDS tiles (16B-aligned)
#define NJOBS 33

typedef __attribute__((ext_vector_type(8))) __bf16 bf16x8;
typedef __attribute__((ext_vector_type(4))) __bf16 bf16x4;
typedef __attribute__((ext_vector_type(4))) float  f32x4;

struct CastJobs {
    const float* src[NJOBS];
    __bf16*      dst[NJOBS];
    long         n[NJOBS];
    int          startBlk[NJOBS];
};

// fp32 -> bf16 cast, 33 tensors in one launch. 256 thr x 4 elems = 1024/blk.
__global__ void cast_many_k(CastJobs J)
{
    int b = blockIdx.x;
    int j = 0;
#pragma unroll
    for (int t = 0; t < NJOBS; t++) { if (J.startBlk[t] <= b) j = t; }
    long idx = ((long)(b - J.startBlk[j]) * 256 + threadIdx.x) * 4;
    if (idx < J.n[j]) {
        f32x4 v = *(const f32x4*)(J.src[j] + idx);
        bf16x4 o;
        o[0] = (__bf16)v[0]; o[1] = (__bf16)v[1];
        o[2] = (__bf16)v[2]; o[3] = (__bf16)v[3];
        *(bf16x4*)(J.dst[j] + idx) = o;
    }
}

__device__ __forceinline__ void gload_lds16(const __bf16* g, __bf16* l)
{
    __builtin_amdgcn_global_load_lds(
        (const __attribute__((address_space(1))) void*)g,
        (__attribute__((address_space(3))) void*)l, 16, 0, 0);
}

__device__ __forceinline__ float ssilu(float v)
{
    float e = __expf(-fabsf(v));
    float sig = (v >= 0.0f) ? 1.0f / (1.0f + e) : e / (1.0f + e);
    return v * sig * 1.6666666666666667f;
}

// ============================ fused chain kernels ============================
// One GEMM stage on a 64-row LDS tile: acc = X[64,256] @ W^T (W[256,256]
// row-major, read direct from global/L2).  Wave wv owns cols wn..wn+63.
__device__ __forceinline__ void chain_gemm(const __bf16* __restrict__ Xl,
                                           const __bf16* __restrict__ W,
                                           f32x4 (&acc)[4][4],
                                           int wn, int l15, int lq)
{
#pragma unroll
    for (int i = 0; i < 4; i++)
#pragma unroll
        for (int j = 0; j < 4; j++)
#pragma unroll
            for (int r = 0; r < 4; r++) acc[i][j][r] = 0.0f;
#pragma unroll
    for (int k0 = 0; k0 < 8; k0++) {
        bf16x8 af[4], bfr[4];
#pragma unroll
        for (int i = 0; i < 4; i++)
            af[i] = *(const bf16x8*)(Xl + (i * 16 + l15) * XS + k0 * 32 + lq * 8);
#pragma unroll
        for (int j = 0; j < 4; j++)
            bfr[j] = *(const bf16x8*)(W + (long)(wn + j * 16 + l15) * 256 + k0 * 32 + lq * 8);
#pragma unroll
        for (int i = 0; i < 4; i++)
#pragma unroll
            for (int j = 0; j < 4; j++)
                acc[i][j] = __builtin_amdgcn_mfma_f32_16x16x32_bf16(af[i], bfr[j], acc[i][j], 0, 0, 0);
    }
}

// Epilogue: silu (+optional residual from LDS, *1/sqrt2) -> LDS dst tile.
__device__ __forceinline__ void epi_to_lds(const f32x4 (&acc)[4][4],
                                           __bf16* __restrict__ dst,
                                           const __bf16* __restrict__ resL,
                                           int wn, int l15, int lq)
{
#pragma unroll
    for (int i = 0; i < 4; i++)
#pragma unroll
        for (int j = 0; j < 4; j++) {
            int col = wn + j * 16 + l15;
#pragma unroll
            for (int r = 0; r < 4; r++) {
                int row = i * 16 + lq * 4 + r;
                float v = ssilu(acc[i][j][r]);
                if (resL) v = ((float)resL[row * XS + col] + v) * 0.70710678118654752f;
                dst[row * XS + col] = (__bf16)v;
            }
        }
}

// h -> T1 (silu) -> hres (in-place, +h residual) -> K_ (row-major) and
// V^T (transposed) to global.  64 rows/block, grid = TOT/64.
__launch_bounds__(256, 2)
__global__ void fuse_front_k(const __bf16* __restrict__ h,
                             const __bf16* __restrict__ Wp1,
                             const __bf16* __restrict__ Wp2,
                             const __bf16* __restrict__ pWk, const __bf16* __restrict__ pbk,
                             const __bf16* __restrict__ pWv, const __bf16* __restrict__ pbv,
                             __bf16* __restrict__ Kb, __bf16* __restrict__ Vt)
{
    __shared__ __align__(16) __bf16 B0[64 * XS];
    __shared__ __align__(16) __bf16 B1[64 * XS];
    const int tid = threadIdx.x, lane = tid & 63, wv = tid >> 6;
    const int wn = wv * 64, l15 = lane & 15, lq = lane >> 4;
    const long row0 = (long)blockIdx.x * 64;

#pragma unroll
    for (int i = 0; i < 8; i++) {               // h tile -> B0
        int v = tid + i * 256;
        int r = v >> 5, kc = (v & 31) * 8;
        *(bf16x8*)(B0 + r * XS + kc) = *(const bf16x8*)(h + (row0 + r) * 256 + kc);
    }
    __syncthreads();

    f32x4 acc[4][4];
    chain_gemm(B0, Wp1, acc, wn, l15, lq);      // T1 = silu(h@Wp1^T)
    epi_to_lds(acc, B1, nullptr, wn, l15, lq);
    __syncthreads();

    chain_gemm(B1, Wp2, acc, wn, l15, lq);      // hres = (h + silu(T1@Wp2^T))/sqrt2
    __syncthreads();                            // all waves done reading B1
    epi_to_lds(acc, B1, B0, wn, l15, lq);       // in-place into B1
    __syncthreads();

    chain_gemm(B1, pWk, acc, wn, l15, lq);      // K_ = hres@pWk^T + pbk
#pragma unroll
    for (int i = 0; i < 4; i++)
#pragma unroll
        for (int j = 0; j < 4; j++) {
            int col = wn + j * 16 + l15;
            float bc = (float)pbk[col];
#pragma unroll
            for (int r = 0; r < 4; r++) {
                int row = i * 16 + lq * 4 + r;
                Kb[(row0 + row) * 256 + col] = (__bf16)(acc[i][j][r] + bc);
            }
        }

    chain_gemm(B1, pWv, acc, wn, l15, lq);      // V^T[g][c][n] = hres@pWv^T + pbv
    {
        long g   = row0 >> 12;                  // /4096 (64 | 4096: no straddle)
        long n0g = row0 & 4095;
#pragma unroll
        for (int i = 0; i < 4; i++)
#pragma unroll
            for (int j = 0; j < 4; j++) {
                int col = wn + j * 16 + l15;
                float bc = (float)pbv[col];
                long nb = n0g + i * 16 + lq * 4;
                bf16x4 ov;
#pragma unroll
                for (int r = 0; r < 4; r++) ov[r] = (__bf16)(acc[i][j][r] + bc);
                *(bf16x4*)(Vt + ((g * 256 + col) << 12) + nb) = ov;
            }
    }
}

// HB -> t -> tmp -> u (+t res) -> tmp2 -> OUT fp32 (+u res).  grid = TOT/64.
__launch_bounds__(256, 2)
__global__ void fuse_tail_k(const __bf16* __restrict__ HB,
                            const __bf16* __restrict__ Wh,
                            const __bf16* __restrict__ W1a, const __bf16* __restrict__ W1b,
                            const __bf16* __restrict__ W2a, const __bf16* __restrict__ W2b,
                            float* __restrict__ OUT)
{
    __shared__ __align__(16) __bf16 B0[64 * XS];
    __shared__ __align__(16) __bf16 B1[64 * XS];
    const int tid = threadIdx.x, lane = tid & 63, wv = tid >> 6;
    const int wn = wv * 64, l15 = lane & 15, lq = lane >> 4;
    const long row0 = (long)blockIdx.x * 64;

#pragma unroll
    for (int i = 0; i < 8; i++) {               // HB tile -> B0
        int v = tid + i * 256;
        int r = v >> 5, kc = (v & 31) * 8;
        *(bf16x8*)(B0 + r * XS + kc) = *(const bf16x8*)(HB + (row0 + r) * 256 + kc);
    }
    __syncthreads();

    f32x4 acc[4][4];
    chain_gemm(B0, Wh, acc, wn, l15, lq);       // t = silu(HB@Wh^T)
    epi_to_lds(acc, B1, nullptr, wn, l15, lq);
    __syncthreads();

    chain_gemm(B1, W1a, acc, wn, l15, lq);      // tmp = silu(t@W1a^T)
    epi_to_lds(acc, B0, nullptr, wn, l15, lq);  // overwrite HB (readers done)
    __syncthreads();

    chain_gemm(B0, W1b, acc, wn, l15, lq);      // u = (t + silu(tmp@W1b^T))/sqrt2
    __syncthreads();                            // all waves done reading B0
    epi_to_lds(acc, B0, B1, wn, l15, lq);       // in-place, residual = t (B1)
    __syncthreads();

    chain_gemm(B0, W2a, acc, wn, l15, lq);      // tmp2 = silu(u@W2a^T)
    epi_to_lds(acc, B1, nullptr, wn, l15, lq);  // overwrite t (dead)
    __syncthreads();

    chain_gemm(B1, W2b, acc, wn, l15, lq);      // out = (u + silu(tmp2@W2b^T))/sqrt2
#pragma unroll
    for (int i = 0; i < 4; i++)
#pragma unroll
        for (int j = 0; j < 4; j++) {
            int col = wn + j * 16 + l15;
#pragma unroll
            for (int r = 0; r < 4; r++) {
                int row = i * 16 + lq * 4 + r;
                float v = ssilu(acc[i][j][r]);
                v = ((float)B0[row * XS + col] + v) * 0.70710678118654752f;
                OUT[(row0 + row) * 256 + col] = v;
            }
        }
}

// =========================== generic GEMM machinery ==========================
template<int TRANS>
__device__ __forceinline__ bool stage_load(bf16x8 (&rv)[2], __bf16* __restrict__ lds,
                                           const __bf16* __restrict__ G,
                                           int ld, int r0, int Rg,
                                           int k0, int K, int tid)
{
    if (TRANS == 0) {
        const bool fast = ((ld & 7) == 0) && (r0 + BM <= Rg) && (k0 + BKT <= K);
        if (fast) {
#pragma unroll
            for (int i = 0; i < 2; i++) {
                int v = tid + i * 256;            // linear in lane order
                int r = v >> 2, kc = (v & 3) * 8;
                gload_lds16(G + (long)(r0 + r) * ld + (k0 + kc), lds + v * 8);
            }
            return true;
        }
#pragma unroll
        for (int i = 0; i < 2; i++) {
            int v = tid + i * 256;
            int r = v >> 2, kc = (v & 3) * 8;
            int gm = r0 + r, gk = k0 + kc;
            bf16x8 val;
#pragma unroll
            for (int j = 0; j < 8; j++) val[j] = (__bf16)0.0f;
            if (gm < Rg) {
                if (((ld & 7) == 0) && (gk + 8 <= K)) {
                    val = *(const bf16x8*)(G + (long)gm * ld + gk);
                } else {
#pragma unroll
                    for (int j = 0; j < 8; j++)
                        if (gk + j < K) val[j] = G[(long)gm * ld + gk + j];
                }
            }
            rv[i] = val;
        }
        return false;
    } else {
#pragma unroll
        for (int i = 0; i < 2; i++) {
            int v = tid + i * 256;
            int kk = v >> 4;                      // 0..31 k-row
            int mc = (v & 15) * 8;                // m-col group
            int gk = k0 + kk, gm = r0 + mc;
            bf16x8 val;
#pragma unroll
            for (int j = 0; j < 8; j++) val[j] = (__bf16)0.0f;
            if (gk < K) {
                if (((ld & 7) == 0) && (gm + 8 <= Rg)) {
                    val = *(const bf16x8*)(G + (long)gk * ld + gm);
                } else {
#pragma unroll
                    for (int j = 0; j < 8; j++)
                        if (gm + j < Rg) val[j] = G[(long)gk * ld + gm + j];
                }
            }
            rv[i] = val;
        }
        return false;
    }
}

template<int TRANS>
__device__ __forceinline__ void stage_write(const bf16x8 (&rv)[2], __bf16* __restrict__ lds,
                                            int tid, bool fast)
{
    if (TRANS == 0) {
        if (fast) return;
#pragma unroll
        for (int i = 0; i < 2; i++)
            *(bf16x8*)(lds + (tid + i * 256) * 8) = rv[i];   // 16B aligned
    } else {
#pragma unroll
        for (int i = 0; i < 2; i++) {
            int v = tid + i * 256;
            int kk = v >> 4, mc = (v & 15) * 8;
            bf16x4 lo, hi;
            lo[0] = rv[i][0]; lo[1] = rv[i][1]; lo[2] = rv[i][2]; lo[3] = rv[i][3];
            hi[0] = rv[i][4]; hi[1] = rv[i][5]; hi[2] = rv[i][6]; hi[3] = rv[i][7];
            *(bf16x4*)(lds + kk * PKM + mc)     = lo;   // 8B aligned (PKM*2=264)
            *(bf16x4*)(lds + kk * PKM + mc + 4) = hi;
        }
    }
}

template<int AT, int BT>
__device__ __forceinline__ void frag_mfma(const __bf16* __restrict__ Ac,
                                          const __bf16* __restrict__ Bc,
                                          f32x4 (&acc)[4][4],
                                          int wm, int wn, int l15, int lq)
{
    bf16x8 af[4], bfr[4];
    if (AT == 0) {
#pragma unroll
        for (int i = 0; i < 4; i++)
            af[i] = *(const bf16x8*)(Ac + (wm + i * 16 + l15) * BKT + lq * 8);
    } else {
#pragma unroll
        for (int i = 0; i < 4; i++) {
            int m = wm + i * 16 + l15;
#pragma unroll
            for (int j = 0; j < 8; j++) af[i][j] = Ac[(lq * 8 + j) * PKM + m];
        }
    }
    if (BT == 1) {
#pragma unroll
        for (int j = 0; j < 4; j++)
            bfr[j] = *(const bf16x8*)(Bc + (wn + j * 16 + l15) * BKT + lq * 8);
    } else {
#pragma unroll
        for (int j = 0; j < 4; j++) {
            int n = wn + j * 16 + l15;
#pragma unroll
            for (int jj = 0; jj < 8; jj++) bfr[j][jj] = Bc[(lq * 8 + jj) * PKM + n];
        }
    }
#pragma unroll
    for (int i = 0; i < 4; i++)
#pragma unroll
        for (int j = 0; j < 4; j++)
            acc[i][j] = __builtin_amdgcn_mfma_f32_16x16x32_bf16(af[i], bfr[j], acc[i][j], 0, 0, 0);
}

// Generic MFMA GEMM (see prior rounds for parameter semantics).
template<int AT, int BT, int PIPE>
__launch_bounds__(256, 2)
__global__ void gemm_k(const __bf16* __restrict__ A, long aLo, long aHi, int lda, int Ms,
                       const __bf16* __restrict__ Bm, long bLo, long bHi, int ldb, int Ns,
                       const __bf16* __restrict__ bias,
                       const __bf16* __restrict__ res, long rLo, long rHi, int ldr, int resMode,
                       float* __restrict__ outF, __bf16* __restrict__ outB,
                       long oLo, long oHi, int ldo, int storeT,
                       int M, int N, int K, float oscale, int act)
{
    constexpr int BTT = (BT == 1) ? 0 : 1;
    constexpr int NBUF = PIPE ? 2 : 1;
    __shared__ __align__(16) __bf16 As[NBUF * BKT * PKM];
    __shared__ __align__(16) __bf16 Bs[NBUF * BKT * PKM];

    const int tid = threadIdx.x;
    const int z = blockIdx.z;
    const long zl = (long)(z & 31), zh = (long)(z >> 5);
    const __bf16* Ab = A + zl * aLo + zh * aHi;
    const __bf16* Bb = Bm + zl * bLo + zh * bHi;
    const int m0 = blockIdx.x * BM;
    const int n0 = blockIdx.y * BN;

    f32x4 acc[4][4];
#pragma unroll
    for (int i = 0; i < 4; i++)
#pragma unroll
        for (int j = 0; j < 4; j++)
#pragma unroll
            for (int r = 0; r < 4; r++) acc[i][j][r] = 0.0f;

    const int wv = tid >> 6;
    const int lane = tid & 63;
    const int wm = (wv >> 1) * 64;
    const int wn = (wv & 1) * 64;
    const int l15 = lane & 15;
    const int lq  = lane >> 4;

    if (PIPE == 0) {
        for (int k0 = 0; k0 < K; k0 += BKT) {
            bf16x8 ra[2], rb[2];
            bool fa = stage_load<AT>(ra, As, Ab, lda, m0, Ms, k0, K, tid);
            bool fb = stage_load<BTT>(rb, Bs, Bb, ldb, n0, Ns, k0, K, tid);
            stage_write<AT>(ra, As, tid, fa);
            stage_write<BTT>(rb, Bs, tid, fb);
            __syncthreads();
            frag_mfma<AT, BT>(As, Bs, acc, wm, wn, l15, lq);
            __syncthreads();
        }
    } else {
        constexpr int TSZ = BKT * PKM;
        const int nt = (K + BKT - 1) / BKT;
        bf16x8 ra[2], rb[2];
        bool fa = stage_load<AT>(ra, As, Ab, lda, m0, Ms, 0, K, tid);
        bool fb = stage_load<BTT>(rb, Bs, Bb, ldb, n0, Ns, 0, K, tid);
        stage_write<AT>(ra, As, tid, fa);
        stage_write<BTT>(rb, Bs, tid, fb);
        __syncthreads();
        int cur = 0;
        for (int t = 0; t < nt; t++) {
            const bool nxt = (t + 1 < nt);
            if (nxt) {
                fa = stage_load<AT>(ra, As + (cur ^ 1) * TSZ, Ab, lda, m0, Ms, (t + 1) * BKT, K, tid);
                fb = stage_load<BTT>(rb, Bs + (cur ^ 1) * TSZ, Bb, ldb, n0, Ns, (t + 1) * BKT, K, tid);
            }
            frag_mfma<AT, BT>(As + cur * TSZ, Bs + cur * TSZ, acc, wm, wn, l15, lq);
            if (nxt) {
                stage_write<AT>(ra, As + (cur ^ 1) * TSZ, tid, fa);
                stage_write<BTT>(rb, Bs + (cur ^ 1) * TSZ, tid, fb);
                __syncthreads();
                cur ^= 1;
            }
        }
    }

    const __bf16* Rb = res ? (res + zl * rLo + zh * rHi) : (const __bf16*)nullptr;
    const long ob = zl * oLo + zh * oHi;
#pragma unroll
    for (int i = 0; i < 4; i++) {
#pragma unroll
        for (int j = 0; j < 4; j++) {
            int col = n0 + wn + j * 16 + l15;
            if (col >= N) continue;
            float bcol = bias ? (float)bias[col] : 0.0f;
            int row0 = m0 + wm + i * 16 + lq * 4;
            if (!storeT) {
#pragma unroll
                for (int r = 0; r < 4; r++) {
                    int row = row0 + r;
                    if (row >= M) continue;
                    float v = acc[i][j][r] * oscale + bcol;
                    if (act == 1) v = ssilu(v);
                    else if (act == 2) v = fmaxf(v, 0.0f);
                    if (resMode) {
                        float rv = (float)Rb[(long)row * ldr + col];
                        v = (resMode == 1) ? (rv + v) * 0.70710678118654752f : (rv + v);
                    }
                    long oi = ob + (long)row * ldo + col;
                    if (outF) outF[oi] = v;
                    else      outB[oi] = (__bf16)v;
                }
            } else {
                if (row0 + 3 < M) {
                    bf16x4 rv4;
                    if (resMode) rv4 = *(const bf16x4*)(Rb + (long)col * ldr + row0);
                    float vs[4];
#pragma unroll
                    for (int r = 0; r < 4; r++) {
                        float v = acc[i][j][r] * oscale + bcol;
                        if (act == 1) v = ssilu(v);
                        else if (act == 2) v = fmaxf(v, 0.0f);
                        if (resMode) {
                            float rv = (float)rv4[r];
                            v = (resMode == 1) ? (rv + v) * 0.70710678118654752f : (rv + v);
                        }
                        vs[r] = v;
                    }
                    if (outF) {
                        f32x4 o4; o4[0] = vs[0]; o4[1] = vs[1]; o4[2] = vs[2]; o4[3] = vs[3];
                        *(f32x4*)(outF + ob + (long)col * ldo + row0) = o4;
                    } else {
                        bf16x4 ov;
                        ov[0] = (__bf16)vs[0]; ov[1] = (__bf16)vs[1];
                        ov[2] = (__bf16)vs[2]; ov[3] = (__bf16)vs[3];
                        *(bf16x4*)(outB + ob + (long)col * ldo + row0) = ov;
                    }
                } else {
#pragma unroll
                    for (int r = 0; r < 4; r++) {
                        int row = row0 + r;
                        if (row >= M) continue;
                        float v = acc[i][j][r] * oscale + bcol;
                        if (act == 1) v = ssilu(v);
                        else if (act == 2) v = fmaxf(v, 0.0f);
                        if (resMode) {
                            float rv = (float)Rb[(long)col * ldr + row];
                            v = (resMode == 1) ? (rv + v) * 0.70710678118654752f : (rv + v);
                        }
                        if (outF) outF[ob + (long)col * ldo + row] = v;
                        else      outB[ob + (long)col * ldo + row] = (__bf16)v;
                    }
                }
            }
        }
    }
}

// Sum 4 split-K fp32 partials + Qp -> bf16 pooled [32][NS][256].
__global__ void reduce4_k(const float* __restrict__ P, const __bf16* __restrict__ Qp,
                          __bf16* __restrict__ out)
{
    long idx = (long)blockIdx.x * 256 + threadIdx.x;
    long g = idx / (409 * 64);
    long r = idx - g * (409 * 64);
    long s = r >> 6;
    int  c4 = (int)(r & 63) * 4;
    long base = (g * 409 + s) * 256 + c4;
    const long SP = 32L * 409 * 256;
    f32x4 a0 = *(const f32x4*)(P + base);
    f32x4 a1 = *(const f32x4*)(P + base + SP);
    f32x4 a2 = *(const f32x4*)(P + base + 2 * SP);
    f32x4 a3 = *(const f32x4*)(P + base + 3 * SP);
    bf16x4 q = *(const bf16x4*)(Qp + s * 256 + c4);
    bf16x4 o;
#pragma unroll
    for (int k = 0; k < 4; k++)
        o[k] = (__bf16)(a0[k] + a1[k] + a2[k] + a3[k] + (float)q[k]);
    *(bf16x4*)(out + base) = o;
}

// Row softmax over length L (stride ldS fp32 in, ldA bf16 out), zero-fills
// columns [L, Lw).  One wave per row.
__global__ void rowsoftmax_k(const float* __restrict__ S, __bf16* __restrict__ A,
                             long rows, int L, int ldS, int ldA, int Lw)
{
    long row = (long)blockIdx.x * 4 + (threadIdx.x >> 6);
    if (row >= rows) return;
    int lane = threadIdx.x & 63;
    const float* Sr = S + row * (long)ldS;
    float v[7];
    int cnt = 0;
    for (int q = lane; q < L; q += 64) v[cnt++] = Sr[q];
    float m = -3.0e38f;
    for (int c = 0; c < cnt; c++) m = fmaxf(m, v[c]);
#pragma unroll
    for (int off = 32; off > 0; off >>= 1) m = fmaxf(m, __shfl_xor(m, off));
    float s = 0.0f;
    for (int c = 0; c < cnt; c++) s += __expf(v[c] - m);
#pragma unroll
    for (int off = 32; off > 0; off >>= 1) s += __shfl_xor(s, off);
    float inv = 1.0f / s;                  // s >= 1
    cnt = 0;
    for (int q = lane; q < Lw; q += 64) {
        float o = 0.0f;
        if (q < L) { o = __expf(v[cnt] - m) * inv; cnt++; }
        A[row * (long)ldA + q] = (__bf16)o;
    }
}

// LayerNorm over C=256 (eps 1e-5), one wave per row.
__global__ void ln_k(const __bf16* __restrict__ X, __bf16* __restrict__ Y,
                     const __bf16* __restrict__ gamma, const __bf16* __restrict__ beta,
                     int rows)
{
    int row = blockIdx.x * 4 + (threadIdx.x >> 6);
    if (row >= rows) return;
    int lane = threadIdx.x & 63;
    bf16x4 xv = *(const bf16x4*)(X + (long)row * 256 + lane * 4);
    float v0 = (float)xv[0], v1 = (float)xv[1], v2 = (float)xv[2], v3 = (float)xv[3];
    float s = v0 + v1 + v2 + v3;
#pragma unroll
    for (int off = 32; off > 0; off >>= 1) s += __shfl_xor(s, off);
    float mean = s * (1.0f / 256.0f);
    float d0 = v0 - mean, d1 = v1 - mean, d2 = v2 - mean, d3 = v3 - mean;
    float q = d0 * d0 + d1 * d1 + d2 * d2 + d3 * d3;
#pragma unroll
    for (int off = 32; off > 0; off >>= 1) q += __shfl_xor(q, off);
    float sc = rsqrtf(q * (1.0f / 256.0f) + 1e-5f);
    bf16x4 gv = *(const bf16x4*)(gamma + lane * 4);
    bf16x4 bv = *(const bf16x4*)(beta + lane * 4);
    bf16x4 ov;
    ov[0] = (__bf16)(d0 * sc * (float)gv[0] + (float)bv[0]);
    ov[1] = (__bf16)(d1 * sc * (float)gv[1] + (float)bv[1]);
    ov[2] = (__bf16)(d2 * sc * (float)gv[2] + (float)bv[2]);
    ov[3] = (__bf16)(d3 * sc * (float)gv[3] + (float)bv[3]);
    *(bf16x4*)(Y + (long)row * 256 + lane * 4) = ov;
}

// ws too small -> unambiguous sentinel (absmax ~12345), no OOB.
__global__ void sentinel_k(float* out, long n)
{
    long i = (long)blockIdx.x * blockDim.x + threadIdx.x;
    if (i < n) out[i] = 12345.0f;
}

static void G(hipStream_t st, int AT, int BT,
              const __bf16* A, long aLo, long aHi, int lda, int Ms,
              const __bf16* B, long bLo, long bHi, int ldb, int Ns,
              const __bf16* bias,
              const __bf16* res, long rLo, long rHi, int ldr, int resMode,
              float* outF, __bf16* outB, long oLo, long oHi, int ldo, int storeT,
              int M, int N, int K, int Z, float oscale, int act)
{
    dim3 grid((M + BM - 1) / BM, (N + BN - 1) / BN, Z), blk(256, 1, 1);
#define GARGS A, aLo, aHi, lda, Ms, B, bLo, bHi, ldb, Ns, bias, res, rLo, rHi, ldr, resMode, \
              outF, outB, oLo, oHi, ldo, storeT, M, N, K, oscale, act
    if (AT == 0 && BT == 1) {
        gemm_k<0, 1, 0><<<grid, blk, 0, st>>>(GARGS);
    } else if (AT == 0 && BT == 0) {
        if (K >= 512) gemm_k<0, 0, 1><<<grid, blk, 0, st>>>(GARGS);
        else          gemm_k<0, 0, 0><<<grid, blk, 0, st>>>(GARGS);
    } else {
        gemm_k<1, 0, 0><<<grid, blk, 0, st>>>(GARGS);
    }
#undef GARGS
}

extern "C" void kernel_launch(void* const* d_in, const int* in_sizes, int n_in,
                              void* d_out, int out_size, void* d_ws, size_t ws_size,
                              hipStream_t stream)
{
    (void)in_sizes; (void)n_in;
    float* OUT = (float*)d_out;

    const int TOT = 131072, NC = 256, NS = 409, MX = 4096;
    const int NSP = 416;                      // padded NS stride (mult of 8)
    const int NSB = 32 * NS;                  // 13088
    const long NTC = (long)TOT * NC;          // 33.5M elems
    const int GCH = 4;                        // graphs per score chunk

    // ---- param cast table (d_in index -> bf16 param block) ----
    static const int  pidx[NJOBS] = {0,2,3,4,5,6,7,8,9,10,11,12,13,14,15,16,
                                     17,18,19,20,21,22,23,24,25,26,27,28,29,30,31,32,33};
    static const long pn[NJOBS]   = {33554432,65536,65536,104704,
                                     65536,256,65536,256,65536,256,65536,256,
                                     256,256,256,256,
                                     65536,256,65536,256,65536,256,65536,256,
                                     256,256,256,256,
                                     65536,65536,65536,65536,65536};
    long ptot = 0;
    for (int j = 0; j < NJOBS; j++) ptot += pn[j];   // 34,646,272 elems

    char* w = (char*)d_ws;
    size_t off = 0;
    auto take = [&](size_t bytes) -> char* {
        char* p = w + off;
        off += (bytes + 255) & ~(size_t)255;
        return p;
    };
    char* pblk = take((size_t)ptot * 2);                  // 69.3MB bf16 params
    char* reg0 = take((size_t)64 * NS * NSP * 4);         // fp32 scores (43.6MB)
    char* reg1 = take((size_t)32 * MX * NSP * 2);         // A1T (padded)
    char* reg2 = take((size_t)NTC * 2);                   // K_ -> splitK partials -> h_back
    char* reg3 = take((size_t)NTC * 2);                   // V_T -> A2T
    __bf16* QP  = (__bf16*)take((size_t)NS * NC * 2);
    __bf16* sb0 = (__bf16*)take((size_t)NSB * NC * 2);
    __bf16* sb1 = (__bf16*)take((size_t)NSB * NC * 2);
    __bf16* sb2 = (__bf16*)take((size_t)NSB * NC * 2);
    __bf16* sb3 = (__bf16*)take((size_t)NSB * NC * 2);
    __bf16* sb4 = (__bf16*)take((size_t)NSB * NC * 2);
    __bf16* sb5 = (__bf16*)take((size_t)NSB * NC * 2);

    if (off > ws_size) {
        long n = out_size;
        sentinel_k<<<(int)((n + 255) / 256), 256, 0, stream>>>(OUT, n);
        return;
    }

    // Build cast jobs + param pointers.
    CastJobs J;
    __bf16* P[NJOBS];
    {
        long cum = 0;
        int blk = 0;
        for (int j = 0; j < NJOBS; j++) {
            J.src[j] = (const float*)d_in[pidx[j]];
            P[j] = (__bf16*)pblk + cum;
            J.dst[j] = P[j];
            J.n[j] = pn[j];
            J.startBlk[j] = blk;
            blk += (int)((pn[j] + 1023) / 1024);
            cum += pn[j];
        }
        cast_many_k<<<blk, 256, 0, stream>>>(J);
    }
    const __bf16 *hB = P[0], *Wpre1 = P[1], *Wpre2 = P[2], *Sseed = P[3];
    const __bf16 *pWq = P[4], *pbq = P[5], *pWk = P[6], *pbk = P[7];
    const __bf16 *pWv = P[8], *pbv = P[9], *pWo = P[10], *pbo = P[11];
    const __bf16 *pg0 = P[12], *pb0 = P[13], *pg1 = P[14], *pb1 = P[15];
    const __bf16 *iWq = P[16], *ibq = P[17], *iWk = P[18], *ibk = P[19];
    const __bf16 *iWv = P[20], *ibv = P[21], *iWo = P[22], *ibo = P[23];
    const __bf16 *ig0 = P[24], *ib0 = P[25], *ig1 = P[26], *ib1 = P[27];
    const __bf16 *Whead = P[28], *Wr1a = P[29], *Wr1b = P[30];
    const __bf16 *Wr2a = P[31], *Wr2b = P[32];

    float*  STs = (float*)reg0;               // score-T chunk [GCH, MX, NSP] fp32
    float*  S2T = (float*)reg0;               // intra score-T [64, NS, NSP] fp32
    __bf16* A1T = (__bf16*)reg1;              // [32, MX, NSP], pad cols zeroed
    __bf16* Kb  = (__bf16*)reg2;
    float*  PP  = (float*)reg2;               // split-K partials (after K_ dead)
    __bf16* HB  = (__bf16*)reg2;              // h_back (after partials dead)
    __bf16* Vt  = (__bf16*)reg3;              // V_^T [32, 256, 4096]
    __bf16* A2T = (__bf16*)reg3;              // [64, NS, NSP] (after V_T dead)

    // 1-4 fused: h -> T1 -> hres -> {K_, V^T}
    fuse_front_k<<<dim3(TOT / 64), 256, 0, stream>>>(hB, Wpre1, Wpre2,
                                                     pWk, pbk, pWv, pbv, Kb, Vt);
    // 5: Qp = S @ pWq^T + pbq
    G(stream, 0, 1, Sseed, 0, 0, 256, NS, pWq, 0, 0, 256, 256, pbq,
      nullptr, 0, 0, 0, 0, nullptr, QP, 0, 0, 256, 0, NS, 256, 256, 1, 1.0f, 0);
    // 6,7: chunked score-T = K_ @ Qp^T / 16 (fp32, ldo=NSP), ROW softmax -> A1T
    for (int c = 0; c < 32 / GCH; c++) {
        const __bf16* Kc = Kb + (size_t)c * GCH * MX * NC;
        G(stream, 0, 1, Kc, (long)MX * NC, 0, 256, MX, QP, 0, 0, 256, NS, nullptr,
          nullptr, 0, 0, 0, 0, STs, nullptr, (long)MX * NSP, 0, NSP, 0,
          MX, NS, 256, GCH, 0.0625f, 0);
        rowsoftmax_k<<<dim3(GCH * MX / 4), 256, 0, stream>>>(
            STs, A1T + (size_t)c * GCH * MX * NSP, (long)GCH * MX, NS, NSP, NSP, NSP);
    }
    // 8a: split-K x4 partial pooled^T: PP[sp][g][s][c] (fp32, transposed store)
    G(stream, 0, 0, Vt, (long)NC * MX, 1024, MX, NC,
      A1T, (long)MX * NSP, 1024L * NSP, NSP, NSP, nullptr,
      nullptr, 0, 0, 0, 0, PP, nullptr, (long)NS * NC, 32L * NS * NC, NC, 1,
      NC, NS, 1024, 128, 1.0f, 0);
    // 8b: pooled[g][s][c] = Qp[s][c] + sum_sp PP
    reduce4_k<<<dim3((unsigned)((32L * NS * 64) / 256)), 256, 0, stream>>>(PP, QP, sb0);
    // 9-11: LN, +relu(Wo), LN
    ln_k<<<dim3(NSB / 4), 256, 0, stream>>>(sb0, sb1, pg0, pb0, NSB);
    G(stream, 0, 1, sb1, 0, 0, 256, NSB, pWo, 0, 0, 256, 256, pbo,
      sb1, 0, 0, 256, 2, nullptr, sb2, 0, 0, 256, 0, NSB, 256, 256, 1, 1.0f, 2);
    ln_k<<<dim3(NSB / 4), 256, 0, stream>>>(sb2, sb0, pg1, pb1, NSB);
    // 12: Qi, Ki, Vi
    G(stream, 0, 1, sb0, 0, 0, 256, NSB, iWq, 0, 0, 256, 256, ibq,
      nullptr, 0, 0, 0, 0, nullptr, sb1, 0, 0, 256, 0, NSB, 256, 256, 1, 1.0f, 0);
    G(stream, 0, 1, sb0, 0, 0, 256, NSB, iWk, 0, 0, 256, 256, ibk,
      nullptr, 0, 0, 0, 0, nullptr, sb2, 0, 0, 256, 0, NSB, 256, 256, 1, 1.0f, 0);
    G(stream, 0, 1, sb0, 0, 0, 256, NSB, iWv, 0, 0, 256, 256, ibv,
      nullptr, 0, 0, 0, 0, nullptr, sb3, 0, 0, 256, 0, NSB, 256, 256, 1, 1.0f, 0);
    // 13: intra score-T S2T[hb,k,q] = Ki_h @ Qi_h^T / 16  (z = head*32 + b)
    G(stream, 0, 1, sb2, (long)NS * NC, 128, 256, NS, sb1, (long)NS * NC, 128, 256, NS, nullptr,
      nullptr, 0, 0, 0, 0, S2T, nullptr, (long)NS * NSP, 32L * NS * NSP, NSP, 0,
      NS, NS, 128, 64, 0.0625f, 0);
    // 14: A2T = row softmax over q (pad zeroed)
    rowsoftmax_k<<<dim3(64 * NS / 4), 256, 0, stream>>>(S2T, A2T, 64L * NS, NS, NSP, NSP, NSP);
    // 15: out2 = Qi_head + A2 @ Vi_head   (A2[q,k] = A2T[k,q]: AT=1, lda=NSP)
    G(stream, 1, 0, A2T, (long)NS * NSP, 32L * NS * NSP, NSP, NSP,
      sb3, (long)NS * NC, 128, 256, 128, nullptr,
      sb1, (long)NS * NC, 128, 256, 2, nullptr, sb4, (long)NS * NC, 128, 256, 0,
      NS, 128, NS, 64, 1.0f, 0);
    // 16: LN, +relu(iWo), LN -> NAs2 (sb1)
    ln_k<<<dim3(NSB / 4), 256, 0, stream>>>(sb4, sb5, ig0, ib0, NSB);
    G(stream, 0, 1, sb5, 0, 0, 256, NSB, iWo, 0, 0, 256, 256, ibo,
      sb5, 0, 0, 256, 2, nullptr, sb4, 0, 0, 256, 0, NSB, 256, 256, 1, 1.0f, 2);
    ln_k<<<dim3(NSB / 4), 256, 0, stream>>>(sb4, sb1, ig1, ib1, NSB);
    // 17: h_back[n,c] = sum_s A1T[n,s] * NAs2[s,c]; K=416 (A1T pad cols zero)
    G(stream, 0, 0, A1T, (long)MX * NSP, 0, NSP, MX, sb1, (long)NS * NC, 0, 256, 256, nullptr,
      nullptr, 0, 0, 0, 0, nullptr, HB, (long)MX * NC, 0, 256, 0, MX, 256, 416, 32, 1.0f, 0);
    // 18-20 fused: HB -> t -> tmp -> u -> tmp2 -> OUT (fp32)
    fuse_tail_k<<<dim3(TOT / 64), 256, 0, stream>>>(HB, Whead, Wr1a, Wr1b,
                                                    Wr2a, Wr2b, OUT);
}

// Round 5
// 1441.679 us; speedup vs baseline: 1.3242x; 1.0284x over previous
//
#include <hip/hip_runtime.h>

// ---------------------------------------------------------------------------
// NeuralAtom forward, MI355X (gfx950).  FP32 in/out, bf16 MFMA compute.
// B=32 graphs, MAXN=4096, C=256, NS=409 seeds. to_dense_batch == identity.
// This revision: epilogue-vectorized fused chains.
//  - chain_gemmT computes Y^T tiles via mfma(W_frag, X_frag): lane holds 4
//    CONSECUTIVE COLS of Y for a fixed row -> bf16x4/f32x4 stores, register
//    residuals (no LDS re-read), 16x fewer LDS write instrs.
//  - ssilu via rcp (no branch/divide).
// Carried: fuse_front/fuse_tail chain fusion, split-K x4 step 8 + reduce,
// NSP=416 padded attn strides, TRANS=1 [k][PKM] staging, gload_lds width-16.
// ---------------------------------------------------------------------------

#define BM 128
#define BN 128
#define BKT 32
#define PKM 132   // padded m-stride for TRANS=1 [k][m] LDS tiles
#define XS  264   // padded row stride for fused-chain LDS tiles (16B-aligned)
#define NJOBS 33

typedef __attribute__((ext_vector_type(8))) __bf16 bf16x8;
typedef __attribute__((ext_vector_type(4))) __bf16 bf16x4;
typedef __attribute__((ext_vector_type(4))) float  f32x4;

struct CastJobs {
    const float* src[NJOBS];
    __bf16*      dst[NJOBS];
    long         n[NJOBS];
    int          startBlk[NJOBS];
};

// fp32 -> bf16 cast, 33 tensors in one launch. 256 thr x 4 elems = 1024/blk.
__global__ void cast_many_k(CastJobs J)
{
    int b = blockIdx.x;
    int j = 0;
#pragma unroll
    for (int t = 0; t < NJOBS; t++) { if (J.startBlk[t] <= b) j = t; }
    long idx = ((long)(b - J.startBlk[j]) * 256 + threadIdx.x) * 4;
    if (idx < J.n[j]) {
        f32x4 v = *(const f32x4*)(J.src[j] + idx);
        bf16x4 o;
        o[0] = (__bf16)v[0]; o[1] = (__bf16)v[1];
        o[2] = (__bf16)v[2]; o[3] = (__bf16)v[3];
        *(bf16x4*)(J.dst[j] + idx) = o;
    }
}

__device__ __forceinline__ void gload_lds16(const __bf16* g, __bf16* l)
{
    __builtin_amdgcn_global_load_lds(
        (const __attribute__((address_space(1))) void*)g,
        (__attribute__((address_space(3))) void*)l, 16, 0, 0);
}

// scaled SiLU, branch-free.  exp(-v)->inf for very negative v => rcp->0 => -0,
// matching silu -> 0.  rcp rel-err ~1e-7 << bf16 rounding.
__device__ __forceinline__ float ssilu(float v)
{
    float ex = __expf(-v);
    return v * __builtin_amdgcn_rcpf(1.0f + ex) * 1.6666666666666667f;
}

// ============================ fused chain kernels ============================
// Y = X[64,256] @ W^T, computed as Y^T tiles: mfma(A=W_frag, B=X_frag).
// Lane mapping of acc[i][j]: Y row r = j*16 + (lane&15),
//                            Y col c = wn + i*16 + (lane>>4)*4 + reg.
__device__ __forceinline__ void chain_gemmT(const __bf16* __restrict__ Xl,
                                            const __bf16* __restrict__ W,
                                            f32x4 (&acc)[4][4],
                                            int wn, int l15, int lq)
{
#pragma unroll
    for (int i = 0; i < 4; i++)
#pragma unroll
        for (int j = 0; j < 4; j++)
#pragma unroll
            for (int r = 0; r < 4; r++) acc[i][j][r] = 0.0f;
#pragma unroll
    for (int k0 = 0; k0 < 8; k0++) {
        bf16x8 wf[4], xf[4];
#pragma unroll
        for (int i = 0; i < 4; i++)
            wf[i] = *(const bf16x8*)(W + (long)(wn + i * 16 + l15) * 256 + k0 * 32 + lq * 8);
#pragma unroll
        for (int j = 0; j < 4; j++)
            xf[j] = *(const bf16x8*)(Xl + (j * 16 + l15) * XS + k0 * 32 + lq * 8);
#pragma unroll
        for (int i = 0; i < 4; i++)
#pragma unroll
            for (int j = 0; j < 4; j++)
                acc[i][j] = __builtin_amdgcn_mfma_f32_16x16x32_bf16(wf[i], xf[j], acc[i][j], 0, 0, 0);
    }
}

// Old orientation (lane holds 4 consecutive ROWS for fixed col) — used only
// for the V^T transposed global store in fuse_front_k.
__device__ __forceinline__ void chain_gemm(const __bf16* __restrict__ Xl,
                                           const __bf16* __restrict__ W,
                                           f32x4 (&acc)[4][4],
                                           int wn, int l15, int lq)
{
#pragma unroll
    for (int i = 0; i < 4; i++)
#pragma unroll
        for (int j = 0; j < 4; j++)
#pragma unroll
            for (int r = 0; r < 4; r++) acc[i][j][r] = 0.0f;
#pragma unroll
    for (int k0 = 0; k0 < 8; k0++) {
        bf16x8 af[4], bfr[4];
#pragma unroll
        for (int i = 0; i < 4; i++)
            af[i] = *(const bf16x8*)(Xl + (i * 16 + l15) * XS + k0 * 32 + lq * 8);
#pragma unroll
        for (int j = 0; j < 4; j++)
            bfr[j] = *(const bf16x8*)(W + (long)(wn + j * 16 + l15) * 256 + k0 * 32 + lq * 8);
#pragma unroll
        for (int i = 0; i < 4; i++)
#pragma unroll
            for (int j = 0; j < 4; j++)
                acc[i][j] = __builtin_amdgcn_mfma_f32_16x16x32_bf16(af[i], bfr[j], acc[i][j], 0, 0, 0);
    }
}

// h -> T1 (silu) -> hres (+h residual) -> K_ (row-major) and V^T to global.
// 64 rows/block, grid = TOT/64.
__launch_bounds__(256, 2)
__global__ void fuse_front_k(const __bf16* __restrict__ h,
                             const __bf16* __restrict__ Wp1,
                             const __bf16* __restrict__ Wp2,
                             const __bf16* __restrict__ pWk, const __bf16* __restrict__ pbk,
                             const __bf16* __restrict__ pWv, const __bf16* __restrict__ pbv,
                             __bf16* __restrict__ Kb, __bf16* __restrict__ Vt)
{
    __shared__ __align__(16) __bf16 B0[64 * XS];
    __shared__ __align__(16) __bf16 B1[64 * XS];
    const int tid = threadIdx.x, lane = tid & 63, wv = tid >> 6;
    const int wn = wv * 64, l15 = lane & 15, lq = lane >> 4;
    const long row0 = (long)blockIdx.x * 64;

#pragma unroll
    for (int i = 0; i < 8; i++) {               // h tile -> B0
        int v = tid + i * 256;
        int r = v >> 5, kc = (v & 31) * 8;
        *(bf16x8*)(B0 + r * XS + kc) = *(const bf16x8*)(h + (row0 + r) * 256 + kc);
    }
    __syncthreads();

    f32x4 acc[4][4];
    // stage 1: T1 = ssilu(h @ Wp1^T) -> B1
    chain_gemmT(B0, Wp1, acc, wn, l15, lq);
#pragma unroll
    for (int j = 0; j < 4; j++) {
        int r = j * 16 + l15;
#pragma unroll
        for (int i = 0; i < 4; i++) {
            int c0 = wn + i * 16 + lq * 4;
            bf16x4 o;
#pragma unroll
            for (int t = 0; t < 4; t++) o[t] = (__bf16)ssilu(acc[i][j][t]);
            *(bf16x4*)(B1 + r * XS + c0) = o;
        }
    }
    __syncthreads();

    // stage 2: hres = (h + ssilu(T1 @ Wp2^T))/sqrt2 -> B0 (in-place per-thread)
    chain_gemmT(B1, Wp2, acc, wn, l15, lq);
#pragma unroll
    for (int j = 0; j < 4; j++) {
        int r = j * 16 + l15;
#pragma unroll
        for (int i = 0; i < 4; i++) {
            int c0 = wn + i * 16 + lq * 4;
            bf16x4 hv = *(const bf16x4*)(B0 + r * XS + c0);
            bf16x4 o;
#pragma unroll
            for (int t = 0; t < 4; t++)
                o[t] = (__bf16)(((float)hv[t] + ssilu(acc[i][j][t])) * 0.70710678118654752f);
            *(bf16x4*)(B0 + r * XS + c0) = o;
        }
    }
    __syncthreads();

    // stage 3: K_ = hres @ pWk^T + pbk -> global, contiguous bf16x4
    chain_gemmT(B0, pWk, acc, wn, l15, lq);
#pragma unroll
    for (int j = 0; j < 4; j++) {
        int r = j * 16 + l15;
#pragma unroll
        for (int i = 0; i < 4; i++) {
            int c0 = wn + i * 16 + lq * 4;
            bf16x4 bb = *(const bf16x4*)(pbk + c0);
            bf16x4 o;
#pragma unroll
            for (int t = 0; t < 4; t++) o[t] = (__bf16)(acc[i][j][t] + (float)bb[t]);
            *(bf16x4*)(Kb + (row0 + r) * 256 + c0) = o;
        }
    }

    // stage 4: V^T[g][c][n] = hres @ pWv^T + pbv (old orientation: vec along n)
    chain_gemm(B0, pWv, acc, wn, l15, lq);
    {
        long g   = row0 >> 12;                  // /4096 (64 | 4096: no straddle)
        long n0g = row0 & 4095;
#pragma unroll
        for (int i = 0; i < 4; i++)
#pragma unroll
            for (int j = 0; j < 4; j++) {
                int col = wn + j * 16 + l15;
                float bc = (float)pbv[col];
                long nb = n0g + i * 16 + lq * 4;
                bf16x4 ov;
#pragma unroll
                for (int r = 0; r < 4; r++) ov[r] = (__bf16)(acc[i][j][r] + bc);
                *(bf16x4*)(Vt + ((g * 256 + col) << 12) + nb) = ov;
            }
    }
}

// HB -> t -> tmp -> u (+t reg-res) -> tmp2 -> OUT fp32 (+u reg-res).
__launch_bounds__(256, 2)
__global__ void fuse_tail_k(const __bf16* __restrict__ HB,
                            const __bf16* __restrict__ Wh,
                            const __bf16* __restrict__ W1a, const __bf16* __restrict__ W1b,
                            const __bf16* __restrict__ W2a, const __bf16* __restrict__ W2b,
                            float* __restrict__ OUT)
{
    __shared__ __align__(16) __bf16 B0[64 * XS];
    __shared__ __align__(16) __bf16 B1[64 * XS];
    const int tid = threadIdx.x, lane = tid & 63, wv = tid >> 6;
    const int wn = wv * 64, l15 = lane & 15, lq = lane >> 4;
    const long row0 = (long)blockIdx.x * 64;

#pragma unroll
    for (int i = 0; i < 8; i++) {               // HB tile -> B0
        int v = tid + i * 256;
        int r = v >> 5, kc = (v & 31) * 8;
        *(bf16x8*)(B0 + r * XS + kc) = *(const bf16x8*)(HB + (row0 + r) * 256 + kc);
    }
    __syncthreads();

    f32x4 acc[4][4];
    bf16x4 tres[4][4], ures[4][4];

    // stage 1: t = ssilu(HB@Wh^T) -> B1, keep in regs
    chain_gemmT(B0, Wh, acc, wn, l15, lq);
#pragma unroll
    for (int j = 0; j < 4; j++) {
        int r = j * 16 + l15;
#pragma unroll
        for (int i = 0; i < 4; i++) {
            int c0 = wn + i * 16 + lq * 4;
            bf16x4 o;
#pragma unroll
            for (int t = 0; t < 4; t++) o[t] = (__bf16)ssilu(acc[i][j][t]);
            tres[i][j] = o;
            *(bf16x4*)(B1 + r * XS + c0) = o;
        }
    }
    __syncthreads();

    // stage 2: tmp = ssilu(t@W1a^T) -> B0
    chain_gemmT(B1, W1a, acc, wn, l15, lq);
#pragma unroll
    for (int j = 0; j < 4; j++) {
        int r = j * 16 + l15;
#pragma unroll
        for (int i = 0; i < 4; i++) {
            int c0 = wn + i * 16 + lq * 4;
            bf16x4 o;
#pragma unroll
            for (int t = 0; t < 4; t++) o[t] = (__bf16)ssilu(acc[i][j][t]);
            *(bf16x4*)(B0 + r * XS + c0) = o;
        }
    }
    __syncthreads();

    // stage 3: u = (t + ssilu(tmp@W1b^T))/sqrt2 -> B1, keep in regs
    chain_gemmT(B0, W1b, acc, wn, l15, lq);
#pragma unroll
    for (int j = 0; j < 4; j++) {
        int r = j * 16 + l15;
#pragma unroll
        for (int i = 0; i < 4; i++) {
            int c0 = wn + i * 16 + lq * 4;
            bf16x4 o;
#pragma unroll
            for (int t = 0; t < 4; t++)
                o[t] = (__bf16)(((float)tres[i][j][t] + ssilu(acc[i][j][t])) * 0.70710678118654752f);
            ures[i][j] = o;
            *(bf16x4*)(B1 + r * XS + c0) = o;
        }
    }
    __syncthreads();

    // stage 4: tmp2 = ssilu(u@W2a^T) -> B0
    chain_gemmT(B1, W2a, acc, wn, l15, lq);
#pragma unroll
    for (int j = 0; j < 4; j++) {
        int r = j * 16 + l15;
#pragma unroll
        for (int i = 0; i < 4; i++) {
            int c0 = wn + i * 16 + lq * 4;
            bf16x4 o;
#pragma unroll
            for (int t = 0; t < 4; t++) o[t] = (__bf16)ssilu(acc[i][j][t]);
            *(bf16x4*)(B0 + r * XS + c0) = o;
        }
    }
    __syncthreads();

    // stage 5: out = (u + ssilu(tmp2@W2b^T))/sqrt2 -> OUT fp32, f32x4 stores
    chain_gemmT(B0, W2b, acc, wn, l15, lq);
#pragma unroll
    for (int j = 0; j < 4; j++) {
        int r = j * 16 + l15;
#pragma unroll
        for (int i = 0; i < 4; i++) {
            int c0 = wn + i * 16 + lq * 4;
            f32x4 ov;
#pragma unroll
            for (int t = 0; t < 4; t++)
                ov[t] = ((float)ures[i][j][t] + ssilu(acc[i][j][t])) * 0.70710678118654752f;
            *(f32x4*)(OUT + (row0 + r) * 256 + c0) = ov;
        }
    }
}

// =========================== generic GEMM machinery ==========================
template<int TRANS>
__device__ __forceinline__ bool stage_load(bf16x8 (&rv)[2], __bf16* __restrict__ lds,
                                           const __bf16* __restrict__ G,
                                           int ld, int r0, int Rg,
                                           int k0, int K, int tid)
{
    if (TRANS == 0) {
        const bool fast = ((ld & 7) == 0) && (r0 + BM <= Rg) && (k0 + BKT <= K);
        if (fast) {
#pragma unroll
            for (int i = 0; i < 2; i++) {
                int v = tid + i * 256;            // linear in lane order
                int r = v >> 2, kc = (v & 3) * 8;
                gload_lds16(G + (long)(r0 + r) * ld + (k0 + kc), lds + v * 8);
            }
            return true;
        }
#pragma unroll
        for (int i = 0; i < 2; i++) {
            int v = tid + i * 256;
            int r = v >> 2, kc = (v & 3) * 8;
            int gm = r0 + r, gk = k0 + kc;
            bf16x8 val;
#pragma unroll
            for (int j = 0; j < 8; j++) val[j] = (__bf16)0.0f;
            if (gm < Rg) {
                if (((ld & 7) == 0) && (gk + 8 <= K)) {
                    val = *(const bf16x8*)(G + (long)gm * ld + gk);
                } else {
#pragma unroll
                    for (int j = 0; j < 8; j++)
                        if (gk + j < K) val[j] = G[(long)gm * ld + gk + j];
                }
            }
            rv[i] = val;
        }
        return false;
    } else {
#pragma unroll
        for (int i = 0; i < 2; i++) {
            int v = tid + i * 256;
            int kk = v >> 4;                      // 0..31 k-row
            int mc = (v & 15) * 8;                // m-col group
            int gk = k0 + kk, gm = r0 + mc;
            bf16x8 val;
#pragma unroll
            for (int j = 0; j < 8; j++) val[j] = (__bf16)0.0f;
            if (gk < K) {
                if (((ld & 7) == 0) && (gm + 8 <= Rg)) {
                    val = *(const bf16x8*)(G + (long)gk * ld + gm);
                } else {
#pragma unroll
                    for (int j = 0; j < 8; j++)
                        if (gm + j < Rg) val[j] = G[(long)gk * ld + gm + j];
                }
            }
            rv[i] = val;
        }
        return false;
    }
}

template<int TRANS>
__device__ __forceinline__ void stage_write(const bf16x8 (&rv)[2], __bf16* __restrict__ lds,
                                            int tid, bool fast)
{
    if (TRANS == 0) {
        if (fast) return;
#pragma unroll
        for (int i = 0; i < 2; i++)
            *(bf16x8*)(lds + (tid + i * 256) * 8) = rv[i];   // 16B aligned
    } else {
#pragma unroll
        for (int i = 0; i < 2; i++) {
            int v = tid + i * 256;
            int kk = v >> 4, mc = (v & 15) * 8;
            bf16x4 lo, hi;
            lo[0] = rv[i][0]; lo[1] = rv[i][1]; lo[2] = rv[i][2]; lo[3] = rv[i][3];
            hi[0] = rv[i][4]; hi[1] = rv[i][5]; hi[2] = rv[i][6]; hi[3] = rv[i][7];
            *(bf16x4*)(lds + kk * PKM + mc)     = lo;   // 8B aligned (PKM*2=264)
            *(bf16x4*)(lds + kk * PKM + mc + 4) = hi;
        }
    }
}

template<int AT, int BT>
__device__ __forceinline__ void frag_mfma(const __bf16* __restrict__ Ac,
                                          const __bf16* __restrict__ Bc,
                                          f32x4 (&acc)[4][4],
                                          int wm, int wn, int l15, int lq)
{
    bf16x8 af[4], bfr[4];
    if (AT == 0) {
#pragma unroll
        for (int i = 0; i < 4; i++)
            af[i] = *(const bf16x8*)(Ac + (wm + i * 16 + l15) * BKT + lq * 8);
    } else {
#pragma unroll
        for (int i = 0; i < 4; i++) {
            int m = wm + i * 16 + l15;
#pragma unroll
            for (int j = 0; j < 8; j++) af[i][j] = Ac[(lq * 8 + j) * PKM + m];
        }
    }
    if (BT == 1) {
#pragma unroll
        for (int j = 0; j < 4; j++)
            bfr[j] = *(const bf16x8*)(Bc + (wn + j * 16 + l15) * BKT + lq * 8);
    } else {
#pragma unroll
        for (int j = 0; j < 4; j++) {
            int n = wn + j * 16 + l15;
#pragma unroll
            for (int jj = 0; jj < 8; jj++) bfr[j][jj] = Bc[(lq * 8 + jj) * PKM + n];
        }
    }
#pragma unroll
    for (int i = 0; i < 4; i++)
#pragma unroll
        for (int j = 0; j < 4; j++)
            acc[i][j] = __builtin_amdgcn_mfma_f32_16x16x32_bf16(af[i], bfr[j], acc[i][j], 0, 0, 0);
}

// Generic MFMA GEMM (see prior rounds for parameter semantics).
template<int AT, int BT, int PIPE>
__launch_bounds__(256, 2)
__global__ void gemm_k(const __bf16* __restrict__ A, long aLo, long aHi, int lda, int Ms,
                       const __bf16* __restrict__ Bm, long bLo, long bHi, int ldb, int Ns,
                       const __bf16* __restrict__ bias,
                       const __bf16* __restrict__ res, long rLo, long rHi, int ldr, int resMode,
                       float* __restrict__ outF, __bf16* __restrict__ outB,
                       long oLo, long oHi, int ldo, int storeT,
                       int M, int N, int K, float oscale, int act)
{
    constexpr int BTT = (BT == 1) ? 0 : 1;
    constexpr int NBUF = PIPE ? 2 : 1;
    __shared__ __align__(16) __bf16 As[NBUF * BKT * PKM];
    __shared__ __align__(16) __bf16 Bs[NBUF * BKT * PKM];

    const int tid = threadIdx.x;
    const int z = blockIdx.z;
    const long zl = (long)(z & 31), zh = (long)(z >> 5);
    const __bf16* Ab = A + zl * aLo + zh * aHi;
    const __bf16* Bb = Bm + zl * bLo + zh * bHi;
    const int m0 = blockIdx.x * BM;
    const int n0 = blockIdx.y * BN;

    f32x4 acc[4][4];
#pragma unroll
    for (int i = 0; i < 4; i++)
#pragma unroll
        for (int j = 0; j < 4; j++)
#pragma unroll
            for (int r = 0; r < 4; r++) acc[i][j][r] = 0.0f;

    const int wv = tid >> 6;
    const int lane = tid & 63;
    const int wm = (wv >> 1) * 64;
    const int wn = (wv & 1) * 64;
    const int l15 = lane & 15;
    const int lq  = lane >> 4;

    if (PIPE == 0) {
        for (int k0 = 0; k0 < K; k0 += BKT) {
            bf16x8 ra[2], rb[2];
            bool fa = stage_load<AT>(ra, As, Ab, lda, m0, Ms, k0, K, tid);
            bool fb = stage_load<BTT>(rb, Bs, Bb, ldb, n0, Ns, k0, K, tid);
            stage_write<AT>(ra, As, tid, fa);
            stage_write<BTT>(rb, Bs, tid, fb);
            __syncthreads();
            frag_mfma<AT, BT>(As, Bs, acc, wm, wn, l15, lq);
            __syncthreads();
        }
    } else {
        constexpr int TSZ = BKT * PKM;
        const int nt = (K + BKT - 1) / BKT;
        bf16x8 ra[2], rb[2];
        bool fa = stage_load<AT>(ra, As, Ab, lda, m0, Ms, 0, K, tid);
        bool fb = stage_load<BTT>(rb, Bs, Bb, ldb, n0, Ns, 0, K, tid);
        stage_write<AT>(ra, As, tid, fa);
        stage_write<BTT>(rb, Bs, tid, fb);
        __syncthreads();
        int cur = 0;
        for (int t = 0; t < nt; t++) {
            const bool nxt = (t + 1 < nt);
            if (nxt) {
                fa = stage_load<AT>(ra, As + (cur ^ 1) * TSZ, Ab, lda, m0, Ms, (t + 1) * BKT, K, tid);
                fb = stage_load<BTT>(rb, Bs + (cur ^ 1) * TSZ, Bb, ldb, n0, Ns, (t + 1) * BKT, K, tid);
            }
            frag_mfma<AT, BT>(As + cur * TSZ, Bs + cur * TSZ, acc, wm, wn, l15, lq);
            if (nxt) {
                stage_write<AT>(ra, As + (cur ^ 1) * TSZ, tid, fa);
                stage_write<BTT>(rb, Bs + (cur ^ 1) * TSZ, tid, fb);
                __syncthreads();
                cur ^= 1;
            }
        }
    }

    const __bf16* Rb = res ? (res + zl * rLo + zh * rHi) : (const __bf16*)nullptr;
    const long ob = zl * oLo + zh * oHi;
#pragma unroll
    for (int i = 0; i < 4; i++) {
#pragma unroll
        for (int j = 0; j < 4; j++) {
            int col = n0 + wn + j * 16 + l15;
            if (col >= N) continue;
            float bcol = bias ? (float)bias[col] : 0.0f;
            int row0 = m0 + wm + i * 16 + lq * 4;
            if (!storeT) {
#pragma unroll
                for (int r = 0; r < 4; r++) {
                    int row = row0 + r;
                    if (row >= M) continue;
                    float v = acc[i][j][r] * oscale + bcol;
                    if (act == 1) v = ssilu(v);
                    else if (act == 2) v = fmaxf(v, 0.0f);
                    if (resMode) {
                        float rv = (float)Rb[(long)row * ldr + col];
                        v = (resMode == 1) ? (rv + v) * 0.70710678118654752f : (rv + v);
                    }
                    long oi = ob + (long)row * ldo + col;
                    if (outF) outF[oi] = v;
                    else      outB[oi] = (__bf16)v;
                }
            } else {
                if (row0 + 3 < M) {
                    bf16x4 rv4;
                    if (resMode) rv4 = *(const bf16x4*)(Rb + (long)col * ldr + row0);
                    float vs[4];
#pragma unroll
                    for (int r = 0; r < 4; r++) {
                        float v = acc[i][j][r] * oscale + bcol;
                        if (act == 1) v = ssilu(v);
                        else if (act == 2) v = fmaxf(v, 0.0f);
                        if (resMode) {
                            float rv = (float)rv4[r];
                            v = (resMode == 1) ? (rv + v) * 0.70710678118654752f : (rv + v);
                        }
                        vs[r] = v;
                    }
                    if (outF) {
                        f32x4 o4; o4[0] = vs[0]; o4[1] = vs[1]; o4[2] = vs[2]; o4[3] = vs[3];
                        *(f32x4*)(outF + ob + (long)col * ldo + row0) = o4;
                    } else {
                        bf16x4 ov;
                        ov[0] = (__bf16)vs[0]; ov[1] = (__bf16)vs[1];
                        ov[2] = (__bf16)vs[2]; ov[3] = (__bf16)vs[3];
                        *(bf16x4*)(outB + ob + (long)col * ldo + row0) = ov;
                    }
                } else {
#pragma unroll
                    for (int r = 0; r < 4; r++) {
                        int row = row0 + r;
                        if (row >= M) continue;
                        float v = acc[i][j][r] * oscale + bcol;
                        if (act == 1) v = ssilu(v);
                        else if (act == 2) v = fmaxf(v, 0.0f);
                        if (resMode) {
                            float rv = (float)Rb[(long)col * ldr + row];
                            v = (resMode == 1) ? (rv + v) * 0.70710678118654752f : (rv + v);
                        }
                        if (outF) outF[ob + (long)col * ldo + row] = v;
                        else      outB[ob + (long)col * ldo + row] = (__bf16)v;
                    }
                }
            }
        }
    }
}

// Sum 4 split-K fp32 partials + Qp -> bf16 pooled [32][NS][256].
__global__ void reduce4_k(const float* __restrict__ P, const __bf16* __restrict__ Qp,
                          __bf16* __restrict__ out)
{
    long idx = (long)blockIdx.x * 256 + threadIdx.x;
    long g = idx / (409 * 64);
    long r = idx - g * (409 * 64);
    long s = r >> 6;
    int  c4 = (int)(r & 63) * 4;
    long base = (g * 409 + s) * 256 + c4;
    const long SP = 32L * 409 * 256;
    f32x4 a0 = *(const f32x4*)(P + base);
    f32x4 a1 = *(const f32x4*)(P + base + SP);
    f32x4 a2 = *(const f32x4*)(P + base + 2 * SP);
    f32x4 a3 = *(const f32x4*)(P + base + 3 * SP);
    bf16x4 q = *(const bf16x4*)(Qp + s * 256 + c4);
    bf16x4 o;
#pragma unroll
    for (int k = 0; k < 4; k++)
        o[k] = (__bf16)(a0[k] + a1[k] + a2[k] + a3[k] + (float)q[k]);
    *(bf16x4*)(out + base) = o;
}

// Row softmax over length L (stride ldS fp32 in, ldA bf16 out), zero-fills
// columns [L, Lw).  One wave per row.
__global__ void rowsoftmax_k(const float* __restrict__ S, __bf16* __restrict__ A,
                             long rows, int L, int ldS, int ldA, int Lw)
{
    long row = (long)blockIdx.x * 4 + (threadIdx.x >> 6);
    if (row >= rows) return;
    int lane = threadIdx.x & 63;
    const float* Sr = S + row * (long)ldS;
    float v[7];
    int cnt = 0;
    for (int q = lane; q < L; q += 64) v[cnt++] = Sr[q];
    float m = -3.0e38f;
    for (int c = 0; c < cnt; c++) m = fmaxf(m, v[c]);
#pragma unroll
    for (int off = 32; off > 0; off >>= 1) m = fmaxf(m, __shfl_xor(m, off));
    float s = 0.0f;
    for (int c = 0; c < cnt; c++) s += __expf(v[c] - m);
#pragma unroll
    for (int off = 32; off > 0; off >>= 1) s += __shfl_xor(s, off);
    float inv = 1.0f / s;                  // s >= 1
    cnt = 0;
    for (int q = lane; q < Lw; q += 64) {
        float o = 0.0f;
        if (q < L) { o = __expf(v[cnt] - m) * inv; cnt++; }
        A[row * (long)ldA + q] = (__bf16)o;
    }
}

// LayerNorm over C=256 (eps 1e-5), one wave per row.
__global__ void ln_k(const __bf16* __restrict__ X, __bf16* __restrict__ Y,
                     const __bf16* __restrict__ gamma, const __bf16* __restrict__ beta,
                     int rows)
{
    int row = blockIdx.x * 4 + (threadIdx.x >> 6);
    if (row >= rows) return;
    int lane = threadIdx.x & 63;
    bf16x4 xv = *(const bf16x4*)(X + (long)row * 256 + lane * 4);
    float v0 = (float)xv[0], v1 = (float)xv[1], v2 = (float)xv[2], v3 = (float)xv[3];
    float s = v0 + v1 + v2 + v3;
#pragma unroll
    for (int off = 32; off > 0; off >>= 1) s += __shfl_xor(s, off);
    float mean = s * (1.0f / 256.0f);
    float d0 = v0 - mean, d1 = v1 - mean, d2 = v2 - mean, d3 = v3 - mean;
    float q = d0 * d0 + d1 * d1 + d2 * d2 + d3 * d3;
#pragma unroll
    for (int off = 32; off > 0; off >>= 1) q += __shfl_xor(q, off);
    float sc = rsqrtf(q * (1.0f / 256.0f) + 1e-5f);
    bf16x4 gv = *(const bf16x4*)(gamma + lane * 4);
    bf16x4 bv = *(const bf16x4*)(beta + lane * 4);
    bf16x4 ov;
    ov[0] = (__bf16)(d0 * sc * (float)gv[0] + (float)bv[0]);
    ov[1] = (__bf16)(d1 * sc * (float)gv[1] + (float)bv[1]);
    ov[2] = (__bf16)(d2 * sc * (float)gv[2] + (float)bv[2]);
    ov[3] = (__bf16)(d3 * sc * (float)gv[3] + (float)bv[3]);
    *(bf16x4*)(Y + (long)row * 256 + lane * 4) = ov;
}

// ws too small -> unambiguous sentinel (absmax ~12345), no OOB.
__global__ void sentinel_k(float* out, long n)
{
    long i = (long)blockIdx.x * blockDim.x + threadIdx.x;
    if (i < n) out[i] = 12345.0f;
}

static void G(hipStream_t st, int AT, int BT,
              const __bf16* A, long aLo, long aHi, int lda, int Ms,
              const __bf16* B, long bLo, long bHi, int ldb, int Ns,
              const __bf16* bias,
              const __bf16* res, long rLo, long rHi, int ldr, int resMode,
              float* outF, __bf16* outB, long oLo, long oHi, int ldo, int storeT,
              int M, int N, int K, int Z, float oscale, int act)
{
    dim3 grid((M + BM - 1) / BM, (N + BN - 1) / BN, Z), blk(256, 1, 1);
#define GARGS A, aLo, aHi, lda, Ms, B, bLo, bHi, ldb, Ns, bias, res, rLo, rHi, ldr, resMode, \
              outF, outB, oLo, oHi, ldo, storeT, M, N, K, oscale, act
    if (AT == 0 && BT == 1) {
        gemm_k<0, 1, 0><<<grid, blk, 0, st>>>(GARGS);
    } else if (AT == 0 && BT == 0) {
        if (K >= 512) gemm_k<0, 0, 1><<<grid, blk, 0, st>>>(GARGS);
        else          gemm_k<0, 0, 0><<<grid, blk, 0, st>>>(GARGS);
    } else {
        gemm_k<1, 0, 0><<<grid, blk, 0, st>>>(GARGS);
    }
#undef GARGS
}

extern "C" void kernel_launch(void* const* d_in, const int* in_sizes, int n_in,
                              void* d_out, int out_size, void* d_ws, size_t ws_size,
                              hipStream_t stream)
{
    (void)in_sizes; (void)n_in;
    float* OUT = (float*)d_out;

    const int TOT = 131072, NC = 256, NS = 409, MX = 4096;
    const int NSP = 416;                      // padded NS stride (mult of 8)
    const int NSB = 32 * NS;                  // 13088
    const long NTC = (long)TOT * NC;          // 33.5M elems
    const int GCH = 4;                        // graphs per score chunk

    // ---- param cast table (d_in index -> bf16 param block) ----
    static const int  pidx[NJOBS] = {0,2,3,4,5,6,7,8,9,10,11,12,13,14,15,16,
                                     17,18,19,20,21,22,23,24,25,26,27,28,29,30,31,32,33};
    static const long pn[NJOBS]   = {33554432,65536,65536,104704,
                                     65536,256,65536,256,65536,256,65536,256,
                                     256,256,256,256,
                                     65536,256,65536,256,65536,256,65536,256,
                                     256,256,256,256,
                                     65536,65536,65536,65536,65536};
    long ptot = 0;
    for (int j = 0; j < NJOBS; j++) ptot += pn[j];   // 34,646,272 elems

    char* w = (char*)d_ws;
    size_t off = 0;
    auto take = [&](size_t bytes) -> char* {
        char* p = w + off;
        off += (bytes + 255) & ~(size_t)255;
        return p;
    };
    char* pblk = take((size_t)ptot * 2);                  // 69.3MB bf16 params
    char* reg0 = take((size_t)64 * NS * NSP * 4);         // fp32 scores (43.6MB)
    char* reg1 = take((size_t)32 * MX * NSP * 2);         // A1T (padded)
    char* reg2 = take((size_t)NTC * 2);                   // K_ -> splitK partials -> h_back
    char* reg3 = take((size_t)NTC * 2);                   // V_T -> A2T
    __bf16* QP  = (__bf16*)take((size_t)NS * NC * 2);
    __bf16* sb0 = (__bf16*)take((size_t)NSB * NC * 2);
    __bf16* sb1 = (__bf16*)take((size_t)NSB * NC * 2);
    __bf16* sb2 = (__bf16*)take((size_t)NSB * NC * 2);
    __bf16* sb3 = (__bf16*)take((size_t)NSB * NC * 2);
    __bf16* sb4 = (__bf16*)take((size_t)NSB * NC * 2);
    __bf16* sb5 = (__bf16*)take((size_t)NSB * NC * 2);

    if (off > ws_size) {
        long n = out_size;
        sentinel_k<<<(int)((n + 255) / 256), 256, 0, stream>>>(OUT, n);
        return;
    }

    // Build cast jobs + param pointers.
    CastJobs J;
    __bf16* P[NJOBS];
    {
        long cum = 0;
        int blk = 0;
        for (int j = 0; j < NJOBS; j++) {
            J.src[j] = (const float*)d_in[pidx[j]];
            P[j] = (__bf16*)pblk + cum;
            J.dst[j] = P[j];
            J.n[j] = pn[j];
            J.startBlk[j] = blk;
            blk += (int)((pn[j] + 1023) / 1024);
            cum += pn[j];
        }
        cast_many_k<<<blk, 256, 0, stream>>>(J);
    }
    const __bf16 *hB = P[0], *Wpre1 = P[1], *Wpre2 = P[2], *Sseed = P[3];
    const __bf16 *pWq = P[4], *pbq = P[5], *pWk = P[6], *pbk = P[7];
    const __bf16 *pWv = P[8], *pbv = P[9], *pWo = P[10], *pbo = P[11];
    const __bf16 *pg0 = P[12], *pb0 = P[13], *pg1 = P[14], *pb1 = P[15];
    const __bf16 *iWq = P[16], *ibq = P[17], *iWk = P[18], *ibk = P[19];
    const __bf16 *iWv = P[20], *ibv = P[21], *iWo = P[22], *ibo = P[23];
    const __bf16 *ig0 = P[24], *ib0 = P[25], *ig1 = P[26], *ib1 = P[27];
    const __bf16 *Whead = P[28], *Wr1a = P[29], *Wr1b = P[30];
    const __bf16 *Wr2a = P[31], *Wr2b = P[32];

    float*  STs = (float*)reg0;               // score-T chunk [GCH, MX, NSP] fp32
    float*  S2T = (float*)reg0;               // intra score-T [64, NS, NSP] fp32
    __bf16* A1T = (__bf16*)reg1;              // [32, MX, NSP], pad cols zeroed
    __bf16* Kb  = (__bf16*)reg2;
    float*  PP  = (float*)reg2;               // split-K partials (after K_ dead)
    __bf16* HB  = (__bf16*)reg2;              // h_back (after partials dead)
    __bf16* Vt  = (__bf16*)reg3;              // V_^T [32, 256, 4096]
    __bf16* A2T = (__bf16*)reg3;              // [64, NS, NSP] (after V_T dead)

    // 1-4 fused: h -> T1 -> hres -> {K_, V^T}
    fuse_front_k<<<dim3(TOT / 64), 256, 0, stream>>>(hB, Wpre1, Wpre2,
                                                     pWk, pbk, pWv, pbv, Kb, Vt);
    // 5: Qp = S @ pWq^T + pbq
    G(stream, 0, 1, Sseed, 0, 0, 256, NS, pWq, 0, 0, 256, 256, pbq,
      nullptr, 0, 0, 0, 0, nullptr, QP, 0, 0, 256, 0, NS, 256, 256, 1, 1.0f, 0);
    // 6,7: chunked score-T = K_ @ Qp^T / 16 (fp32, ldo=NSP), ROW softmax -> A1T
    for (int c = 0; c < 32 / GCH; c++) {
        const __bf16* Kc = Kb + (size_t)c * GCH * MX * NC;
        G(stream, 0, 1, Kc, (long)MX * NC, 0, 256, MX, QP, 0, 0, 256, NS, nullptr,
          nullptr, 0, 0, 0, 0, STs, nullptr, (long)MX * NSP, 0, NSP, 0,
          MX, NS, 256, GCH, 0.0625f, 0);
        rowsoftmax_k<<<dim3(GCH * MX / 4), 256, 0, stream>>>(
            STs, A1T + (size_t)c * GCH * MX * NSP, (long)GCH * MX, NS, NSP, NSP, NSP);
    }
    // 8a: split-K x4 partial pooled^T: PP[sp][g][s][c] (fp32, transposed store)
    G(stream, 0, 0, Vt, (long)NC * MX, 1024, MX, NC,
      A1T, (long)MX * NSP, 1024L * NSP, NSP, NSP, nullptr,
      nullptr, 0, 0, 0, 0, PP, nullptr, (long)NS * NC, 32L * NS * NC, NC, 1,
      NC, NS, 1024, 128, 1.0f, 0);
    // 8b: pooled[g][s][c] = Qp[s][c] + sum_sp PP
    reduce4_k<<<dim3((unsigned)((32L * NS * 64) / 256)), 256, 0, stream>>>(PP, QP, sb0);
    // 9-11: LN, +relu(Wo), LN
    ln_k<<<dim3(NSB / 4), 256, 0, stream>>>(sb0, sb1, pg0, pb0, NSB);
    G(stream, 0, 1, sb1, 0, 0, 256, NSB, pWo, 0, 0, 256, 256, pbo,
      sb1, 0, 0, 256, 2, nullptr, sb2, 0, 0, 256, 0, NSB, 256, 256, 1, 1.0f, 2);
    ln_k<<<dim3(NSB / 4), 256, 0, stream>>>(sb2, sb0, pg1, pb1, NSB);
    // 12: Qi, Ki, Vi
    G(stream, 0, 1, sb0, 0, 0, 256, NSB, iWq, 0, 0, 256, 256, ibq,
      nullptr, 0, 0, 0, 0, nullptr, sb1, 0, 0, 256, 0, NSB, 256, 256, 1, 1.0f, 0);
    G(stream, 0, 1, sb0, 0, 0, 256, NSB, iWk, 0, 0, 256, 256, ibk,
      nullptr, 0, 0, 0, 0, nullptr, sb2, 0, 0, 256, 0, NSB, 256, 256, 1, 1.0f, 0);
    G(stream, 0, 1, sb0, 0, 0, 256, NSB, iWv, 0, 0, 256, 256, ibv,
      nullptr, 0, 0, 0, 0, nullptr, sb3, 0, 0, 256, 0, NSB, 256, 256, 1, 1.0f, 0);
    // 13: intra score-T S2T[hb,k,q] = Ki_h @ Qi_h^T / 16  (z = head*32 + b)
    G(stream, 0, 1, sb2, (long)NS * NC, 128, 256, NS, sb1, (long)NS * NC, 128, 256, NS, nullptr,
      nullptr, 0, 0, 0, 0, S2T, nullptr, (long)NS * NSP, 32L * NS * NSP, NSP, 0,
      NS, NS, 128, 64, 0.0625f, 0);
    // 14: A2T = row softmax over q (pad zeroed)
    rowsoftmax_k<<<dim3(64 * NS / 4), 256, 0, stream>>>(S2T, A2T, 64L * NS, NS, NSP, NSP, NSP);
    // 15: out2 = Qi_head + A2 @ Vi_head   (A2[q,k] = A2T[k,q]: AT=1, lda=NSP)
    G(stream, 1, 0, A2T, (long)NS * NSP, 32L * NS * NSP, NSP, NSP,
      sb3, (long)NS * NC, 128, 256, 128, nullptr,
      sb1, (long)NS * NC, 128, 256, 2, nullptr, sb4, (long)NS * NC, 128, 256, 0,
      NS, 128, NS, 64, 1.0f, 0);
    // 16: LN, +relu(iWo), LN -> NAs2 (sb1)
    ln_k<<<dim3(NSB / 4), 256, 0, stream>>>(sb4, sb5, ig0, ib0, NSB);
    G(stream, 0, 1, sb5, 0, 0, 256, NSB, iWo, 0, 0, 256, 256, ibo,
      sb5, 0, 0, 256, 2, nullptr, sb4, 0, 0, 256, 0, NSB, 256, 256, 1, 1.0f, 2);
    ln_k<<<dim3(NSB / 4), 256, 0, stream>>>(sb4, sb1, ig1, ib1, NSB);
    // 17: h_back[n,c] = sum_s A1T[n,s] * NAs2[s,c]; K=416 (A1T pad cols zero)
    G(stream, 0, 0, A1T, (long)MX * NSP, 0, NSP, MX, sb1, (long)NS * NC, 0, 256, 256, nullptr,
      nullptr, 0, 0, 0, 0, nullptr, HB, (long)MX * NC, 0, 256, 0, MX, 256, 416, 32, 1.0f, 0);
    // 18-20 fused: HB -> t -> tmp -> u -> tmp2 -> OUT (fp32)
    fuse_tail_k<<<dim3(TOT / 64), 256, 0, stream>>>(HB, Whead, Wr1a, Wr1b,
                                                    Wr2a, Wr2b, OUT);
}